// Round 10
// baseline (808.146 us; speedup 1.0000x reference)
//
#include <hip/hip_runtime.h>
#include <hip/hip_bf16.h>

// GloAttnConv R21: CHUNK 100 -> 50. k_kvp was 45us at 26% occupancy (grid
// 1024 blocks = 50% wave-slot cap, degraded to 26%) with ~21us VALU-active
// and ~24us unhidden stall. CHUNK=50 -> ~1984 blocks = 97% slot coverage,
// same total VALU work, stalls hidden. (R19's CHUNK=200 was the same lever
// pushed the wrong way.) k_red pays +~3us/iter reading 2x chunk partials.
// Also: k_qkm x-loads via float4 (was 16 scalar dword loads).

typedef __attribute__((ext_vector_type(8))) short bf16x8;
typedef __attribute__((ext_vector_type(4))) float f32x4v;

#define CHUNK 50

__device__ __forceinline__ float asf(unsigned int u) { union { unsigned int i; float f; } v; v.i = u; return v.f; }
__device__ __forceinline__ float b2f_u(unsigned short u) { return asf((unsigned int)u << 16); }
__device__ __forceinline__ unsigned short f2b_u(float f) {
    __hip_bfloat16 h = __float2bfloat16(f);
    union { __hip_bfloat16 h; unsigned short u; } v; v.h = h; return v.u;
}
__device__ __forceinline__ unsigned int pack2(float a, float b) {
    return (unsigned int)f2b_u(a) | ((unsigned int)f2b_u(b) << 16);
}
__device__ __forceinline__ float wave_reduce_sum(float v) {
    #pragma unroll
    for (int off = 32; off > 0; off >>= 1) v += __shfl_xor(v, off, 64);
    return v;
}

// ---- graph bookkeeping: node ptr + chunk ptr + 16-tile ptr ------------------
__global__ void k_ptr(const int* __restrict__ nn, int* __restrict__ ptr,
                      int* __restrict__ cptr, int* __restrict__ tptr, int B) {
    if (threadIdx.x == 0 && blockIdx.x == 0) {
        int s = 0, c = 0, t = 0; ptr[0] = 0; cptr[0] = 0; tptr[0] = 0;
        for (int i = 0; i < B; ++i) {
            s += nn[i]; ptr[i + 1] = s;
            c += (nn[i] + CHUNK - 1) / CHUNK; cptr[i + 1] = c;
            t += (nn[i] + 15) / 16; tptr[i + 1] = t;
        }
    }
}

__global__ void k_batch(const int* __restrict__ ptr, int* __restrict__ batch) {
    int b = blockIdx.x;
    int s = ptr[b], e = ptr[b + 1];
    for (int i = s + threadIdx.x; i < e; i += blockDim.x) batch[i] = b;
}

// ---- W -> bf16 stacked: [0,8192)=Wq, [8192,16384)=Wk, [16384,24576)=Wo ------
__global__ void k_wcvt(const float* __restrict__ Wq_w, const float* __restrict__ Wk_w,
                       const float* __restrict__ Wo_w, unsigned short* __restrict__ Wb) {
    int i = blockIdx.x * 256 + threadIdx.x;
    if (i < 24576) {
        float v = (i < 8192) ? Wq_w[i] : ((i < 16384) ? Wk_w[i - 8192] : Wo_w[i - 16384]);
        Wb[i] = f2b_u(v);
    }
}

// ---- q/k projection via MFMA + L2-normalize; writes q, kq, curA ------------
__global__ __launch_bounds__(256) void k_qkm(
    const float* __restrict__ x, const unsigned short* __restrict__ Wb,
    const float* __restrict__ Wq_b, const float* __restrict__ Wk_b,
    unsigned short* __restrict__ q, unsigned short* __restrict__ kq,
    unsigned short* __restrict__ curA, int N)
{
    int w = threadIdx.x >> 6, l = threadIdx.x & 63;
    int six = l & 15, quad = l >> 4;
    int base = (blockIdx.x * 4 + w) * 16;
    if (base >= N) return;
    int n = base + six;
    int nc = min(n, N - 1);

    const float* xr = x + (size_t)nc * 64;
    float4 xa = *(const float4*)(xr + quad * 8);
    float4 xb = *(const float4*)(xr + quad * 8 + 4);
    float4 xc = *(const float4*)(xr + 32 + quad * 8);
    float4 xd = *(const float4*)(xr + 32 + quad * 8 + 4);
    union { bf16x8 v; unsigned int u[4]; } b0, b1;
    b0.u[0] = pack2(xa.x, xa.y); b0.u[1] = pack2(xa.z, xa.w);
    b0.u[2] = pack2(xb.x, xb.y); b0.u[3] = pack2(xb.z, xb.w);
    b1.u[0] = pack2(xc.x, xc.y); b1.u[1] = pack2(xc.z, xc.w);
    b1.u[2] = pack2(xd.x, xd.y); b1.u[3] = pack2(xd.z, xd.w);
    if (n < N) {
        unsigned short* cr = curA + (size_t)n * 128;
        *(uint4*)(cr + quad * 8)       = make_uint4(b0.u[0], b0.u[1], b0.u[2], b0.u[3]);
        *(uint4*)(cr + 32 + quad * 8)  = make_uint4(b1.u[0], b1.u[1], b1.u[2], b1.u[3]);
        *(uint4*)(cr + 64 + quad * 8)  = make_uint4(b0.u[0], b0.u[1], b0.u[2], b0.u[3]);
        *(uint4*)(cr + 96 + quad * 8)  = make_uint4(b1.u[0], b1.u[1], b1.u[2], b1.u[3]);
    }

    #pragma unroll
    for (int g = 0; g < 4; ++g) {
        f32x4v c[4];
        #pragma unroll
        for (int tt = 0; tt < 4; ++tt) {
            int t = g * 4 + tt;
            const unsigned short* wr = Wb + (size_t)(t * 16 + six) * 64;
            bf16x8 a0 = *(const bf16x8*)(wr + quad * 8);
            bf16x8 a1 = *(const bf16x8*)(wr + 32 + quad * 8);
            f32x4v cc = {0.f, 0.f, 0.f, 0.f};
            cc = __builtin_amdgcn_mfma_f32_16x16x32_bf16(a0, b0.v, cc, 0, 0, 0);
            cc = __builtin_amdgcn_mfma_f32_16x16x32_bf16(a1, b1.v, cc, 0, 0, 0);
            c[tt] = cc;
        }
        const float* bias = (g < 2) ? Wq_b : Wk_b;
        int cb = (g & 1) * 64 + quad * 4;
        float ss = 0.f;
        #pragma unroll
        for (int tt = 0; tt < 4; ++tt)
            #pragma unroll
            for (int r = 0; r < 4; ++r) {
                float v = c[tt][r] + bias[cb + tt * 16 + r];
                c[tt][r] = v;
                ss += v * v;
            }
        ss += __shfl_xor(ss, 16, 64);
        ss += __shfl_xor(ss, 32, 64);
        float sc = rsqrtf(ss);
        if (n < N) {
            unsigned short* dst = ((g < 2) ? q : kq) + (size_t)n * 128;
            #pragma unroll
            for (int tt = 0; tt < 4; ++tt) {
                unsigned int u0 = pack2(c[tt][0] * sc, c[tt][1] * sc);
                unsigned int u1 = pack2(c[tt][2] * sc, c[tt][3] * sc);
                *(uint2*)(dst + cb + tt * 16) = make_uint2(u0, u1);
            }
        }
    }
}

// ---- degree + slot assignment (slot = this edge's index within its row) ----
__global__ void k_deg(const int* __restrict__ row, int* __restrict__ deg,
                      int* __restrict__ slot, int E) {
    int e = blockIdx.x * 256 + threadIdx.x;
    if (e < E) slot[e] = atomicAdd(&deg[row[e]], 1);
}

// ---- exclusive scan of deg -> rowstart (+ dis folded in) -------------------
__global__ void k_scan1(const int* __restrict__ deg, int* __restrict__ rowstart,
                        int* __restrict__ bsum, float* __restrict__ dis, int N) {
    __shared__ int sh[256];
    int t = threadIdx.x, n = blockIdx.x * 256 + t;
    int v = (n < N) ? deg[n] : 0;
    if (n < N) dis[n] = v > 0 ? rsqrtf((float)v) : 0.f;
    sh[t] = v; __syncthreads();
    #pragma unroll
    for (int off = 1; off < 256; off <<= 1) {
        int add = (t >= off) ? sh[t - off] : 0;
        __syncthreads();
        sh[t] += add;
        __syncthreads();
    }
    if (n < N) rowstart[n] = sh[t] - v;
    if (t == 255) bsum[blockIdx.x] = sh[255];
}

__global__ void k_scan2(int* __restrict__ bsum, int nb) {
    __shared__ int sh[512];
    __shared__ int carry;
    int t = threadIdx.x;
    if (t == 0) carry = 0;
    __syncthreads();
    for (int base = 0; base < nb; base += 512) {
        int idx = base + t;
        int v = (idx < nb) ? bsum[idx] : 0;
        sh[t] = v; __syncthreads();
        for (int off = 1; off < 512; off <<= 1) {
            int add = (t >= off) ? sh[t - off] : 0;
            __syncthreads();
            sh[t] += add;
            __syncthreads();
        }
        if (idx < nb) bsum[idx] = sh[t] - v + carry;
        __syncthreads();
        if (t == 0) carry += sh[511];
        __syncthreads();
    }
}

__global__ void k_scan3(int* __restrict__ rowstart, const int* __restrict__ bsum, int N, int E) {
    int n = blockIdx.x * 256 + threadIdx.x;
    if (n < N) rowstart[n] += bsum[blockIdx.x];
    if (n == 0) rowstart[N] = E;
}

// ---- CSR fill: NO atomic (slot precomputed), ONE int4 16B store per edge ---
__global__ void k_fill(const int* __restrict__ eidx, const float* __restrict__ dis,
                       const int* __restrict__ rowstart, const int* __restrict__ slot,
                       int4* __restrict__ csr_pack, const int* __restrict__ eattr, int E) {
    int e = blockIdx.x * 256 + threadIdx.x;
    if (e >= E) return;
    int r = eidx[e], c = eidx[E + e];
    float wv = dis[r] * dis[c];
    int a0 = eattr[e * 3 + 0], a1 = eattr[e * 3 + 1], a2 = eattr[e * 3 + 2];
    int idx = rowstart[r] + slot[e];
    int4 v;
    v.x = c;
    v.y = __float_as_int(wv);
    v.z = a0 | (a1 << 8) | (a2 << 16);
    v.w = 0;
    csr_pack[idx] = v;
}

// ---- msg_edge[n,64] in BF16; bond table in LDS, wave per node --------------
__global__ __launch_bounds__(256) void k_msg(
    const int* __restrict__ rowstart, const int4* __restrict__ csr_pack,
    const float* __restrict__ bond, unsigned short* __restrict__ msgb, int N) {
    __shared__ float bl[1536];
    int t = threadIdx.x, w = t >> 6, l = t & 63;
    for (int i = t; i < 1536; i += 256) bl[i] = bond[i];
    __syncthreads();
    for (int n = blockIdx.x * 4 + w; n < N; n += gridDim.x * 4) {
        int s0 = rowstart[n], s1 = rowstart[n + 1];
        float m = 0.f;
        #pragma unroll 4
        for (int i = s0; i < s1; ++i) {
            int4 pk = csr_pack[i];
            float wv = __int_as_float(pk.y);
            int att = pk.z;
            m += wv * (bl[(att & 255) * 64 + l] + bl[(8 + ((att >> 8) & 255)) * 64 + l]
                     + bl[(16 + (att >> 16)) * 64 + l]);
        }
        msgb[(size_t)n * 64 + l] = f2b_u(m);
    }
}

// ---- ksum stage 1: per-chunk partial (plain stores) ------------------------
__global__ __launch_bounds__(256) void k_ksump(
    const unsigned short* __restrict__ kq, const int* __restrict__ ptr,
    const int* __restrict__ cptr, float* __restrict__ partKS, int B)
{
    int cid = blockIdx.x;
    if (cid >= cptr[B]) return;
    int lo = 0, hi = B - 1;
    while (lo < hi) { int mid = (lo + hi + 1) >> 1; if (cptr[mid] <= cid) lo = mid; else hi = mid - 1; }
    int b = lo;
    int start = ptr[b] + (cid - cptr[b]) * CHUNK;
    int end = min(start + CHUNK, ptr[b + 1]);
    int t = threadIdx.x, r = t >> 7, col = t & 127;
    float a = 0.f;
    for (int n = start + r; n < end; n += 2)
        a += b2f_u(kq[(size_t)n * 128 + col]);
    __shared__ float sh[256];
    sh[t] = a;
    __syncthreads();
    if (t < 128) partKS[(size_t)cid * 128 + t] = sh[t] + sh[t + 128];
}

// ---- ksum stage 2: sum chunk partials per graph ----------------------------
__global__ __launch_bounds__(128) void k_ksr(
    const float* __restrict__ partKS, const int* __restrict__ cptr,
    float* __restrict__ ksum, int B)
{
    int b = blockIdx.x, t = threadIdx.x;
    float s = 0.f;
    int c0 = cptr[b], c1 = cptr[b + 1];
    for (int c = c0; c < c1; ++c) s += partKS[(size_t)c * 128 + t];
    ksum[b * 128 + t] = s;
}

// ---- denom[n][h] = q[n,h,:].ksum[b,h,:] + n_nodes[b] -----------------------
__global__ __launch_bounds__(256) void k_denom(
    const unsigned short* __restrict__ q, const float* __restrict__ ksum,
    const int* __restrict__ batch, const int* __restrict__ nn,
    float* __restrict__ denom, int N)
{
    int w = threadIdx.x >> 6, l = threadIdx.x & 63;
    int n = blockIdx.x * 4 + w;
    if (n >= N) return;
    int b = batch[n];
    float d0 = b2f_u(q[(size_t)n * 128 + l]) * ksum[b * 128 + l];
    float d1 = b2f_u(q[(size_t)n * 128 + 64 + l]) * ksum[b * 128 + 64 + l];
    d0 = wave_reduce_sum(d0);
    d1 = wave_reduce_sum(d1);
    if (l == 0) {
        float nf = (float)nn[b];
        denom[n * 2 + 0] = d0 + nf;
        denom[n * 2 + 1] = d1 + nf;
    }
}

// ---- stage 1: per-chunk partial kv (bf16 partial stores, no atomics) -------
__global__ __launch_bounds__(256) void k_kvp(
    const unsigned short* __restrict__ kq, const unsigned short* __restrict__ cur,
    const int* __restrict__ ptr, const int* __restrict__ cptr,
    unsigned short* __restrict__ partKV, float* __restrict__ partVS, int B)
{
    int cid = blockIdx.x;
    if (cid >= cptr[B]) return;
    int lo = 0, hi = B - 1;
    while (lo < hi) { int mid = (lo + hi + 1) >> 1; if (cptr[mid] <= cid) lo = mid; else hi = mid - 1; }
    int b = lo;
    int start = ptr[b] + (cid - cptr[b]) * CHUNK;
    int end = min(start + CHUNK, ptr[b + 1]);

    int w = threadIdx.x >> 6, l = threadIdx.x & 63;
    int h = w >> 1, dhalf = w & 1;
    int d0 = dhalf * 32 + (l & 7) * 4;
    int e0 = (l >> 3) * 8;
    float a[4][8], va[8];
    #pragma unroll
    for (int i = 0; i < 4; ++i)
        #pragma unroll
        for (int j = 0; j < 8; ++j) a[i][j] = 0.f;
    #pragma unroll
    for (int j = 0; j < 8; ++j) va[j] = 0.f;

    const unsigned short* kp = kq + (size_t)start * 128 + h * 64 + d0;
    const unsigned short* vp = cur + (size_t)start * 128 + h * 64 + e0;
    #pragma unroll 4
    for (int n = start; n < end; ++n) {
        uint2 ku = *(const uint2*)kp;
        uint4 vu = *(const uint4*)vp;
        kp += 128; vp += 128;
        float k0 = asf(ku.x << 16), k1 = asf(ku.x & 0xffff0000u);
        float k2 = asf(ku.y << 16), k3 = asf(ku.y & 0xffff0000u);
        float v[8];
        v[0] = asf(vu.x << 16); v[1] = asf(vu.x & 0xffff0000u);
        v[2] = asf(vu.y << 16); v[3] = asf(vu.y & 0xffff0000u);
        v[4] = asf(vu.z << 16); v[5] = asf(vu.z & 0xffff0000u);
        v[6] = asf(vu.w << 16); v[7] = asf(vu.w & 0xffff0000u);
        #pragma unroll
        for (int j = 0; j < 8; ++j) {
            a[0][j] += k0 * v[j]; a[1][j] += k1 * v[j];
            a[2][j] += k2 * v[j]; a[3][j] += k3 * v[j];
            va[j] += v[j];
        }
    }
    unsigned short* dst = partKV + (size_t)cid * 8192 + h * 4096;
    #pragma unroll
    for (int j = 0; j < 8; ++j) {
        uint2 s2 = make_uint2(pack2(a[0][j], a[1][j]), pack2(a[2][j], a[3][j]));
        *(uint2*)(dst + (e0 + j) * 64 + d0) = s2;
    }
    if (dhalf == 0 && (l & 7) == 0) {
        float* vdst = partVS + (size_t)cid * 128 + h * 64 + e0;
        #pragma unroll
        for (int j = 0; j < 8; ++j) vdst[j] = va[j];
    }
}

// ---- stage 2: sum bf16 partials -> kvT bf16 + vsum (256 blocks) ------------
__global__ __launch_bounds__(256) void k_red(
    const unsigned short* __restrict__ partKV, const float* __restrict__ partVS,
    const int* __restrict__ cptr, unsigned short* __restrict__ kvT_b,
    float* __restrict__ vsum, int B)
{
    int bid = blockIdx.x;
    int gh = bid >> 1, half = bid & 1;
    int g = gh >> 1, h = gh & 1;
    int c0 = cptr[g], c1 = cptr[g + 1];
    int t = threadIdx.x;
    int off = half * 2048 + t * 8;   // element offset within the 4096-elem strip
    float s[8];
    #pragma unroll
    for (int i = 0; i < 8; ++i) s[i] = 0.f;
    for (int c = c0; c < c1; ++c) {
        uint4 u = *(const uint4*)(partKV + (size_t)c * 8192 + h * 4096 + off);
        s[0] += asf(u.x << 16); s[1] += asf(u.x & 0xffff0000u);
        s[2] += asf(u.y << 16); s[3] += asf(u.y & 0xffff0000u);
        s[4] += asf(u.z << 16); s[5] += asf(u.z & 0xffff0000u);
        s[6] += asf(u.w << 16); s[7] += asf(u.w & 0xffff0000u);
    }
    unsigned int u[4];
    #pragma unroll
    for (int i = 0; i < 4; ++i) u[i] = pack2(s[2 * i], s[2 * i + 1]);
    *(uint4*)(kvT_b + (size_t)gh * 4096 + off) = make_uint4(u[0], u[1], u[2], u[3]);
    if (half == 0 && t < 64) {
        float vs = 0.f;
        for (int c = c0; c < c1; ++c) vs += partVS[(size_t)c * 128 + h * 64 + t];
        vsum[g * 128 + h * 64 + t] = vs;
    }
}

// ---- attn via MFMA on graph-aligned 16-node tiles; also adds 0.5*msg -------
__global__ __launch_bounds__(256) void k_attn(
    const unsigned short* __restrict__ q, const unsigned short* __restrict__ kvT,
    const float* __restrict__ vsum, const float* __restrict__ denom,
    const int* __restrict__ ptr, const int* __restrict__ tptr,
    const unsigned short* __restrict__ msgb,
    unsigned short* __restrict__ curB, int B)
{
    int w = threadIdx.x >> 6, l = threadIdx.x & 63;
    int tid = blockIdx.x * 4 + w;
    if (tid >= tptr[B]) return;
    int lo = 0, hi = B - 1;
    while (lo < hi) { int mid = (lo + hi + 1) >> 1; if (tptr[mid] <= tid) lo = mid; else hi = mid - 1; }
    int b0 = lo;
    int start = ptr[b0] + (tid - tptr[b0]) * 16;
    int end = min(start + 16, ptr[b0 + 1]);
    int quad = l >> 4, six = l & 15;
    int n = start + six;        // this lane's node (C column)
    int nc = min(n, end - 1);   // clamped for loads
    bool live = n < end;
    const unsigned short* mrow = msgb + (size_t)nc * 64;
    uint2 me[4];
    #pragma unroll
    for (int et = 0; et < 4; ++et) me[et] = *(const uint2*)(mrow + et * 16 + quad * 4);
    #pragma unroll
    for (int h = 0; h < 2; ++h) {
        const unsigned short* qrow = q + (size_t)nc * 128 + h * 64;
        bf16x8 qb0 = *(const bf16x8*)(qrow + quad * 8);        // B-frag k=quad*8+j
        bf16x8 qb1 = *(const bf16x8*)(qrow + 32 + quad * 8);
        const unsigned short* Bb = kvT + (size_t)(b0 * 2 + h) * 4096;
        float dn = denom[nc * 2 + h];
        const float* vsb = vsum + (b0 * 2 + h) * 64;
        #pragma unroll
        for (int et = 0; et < 4; ++et) {
            const unsigned short* arow = Bb + (size_t)(et * 16 + six) * 64;  // A m=e row
            bf16x8 a0 = *(const bf16x8*)(arow + quad * 8);
            bf16x8 a1 = *(const bf16x8*)(arow + 32 + quad * 8);
            f32x4v c = {0.f, 0.f, 0.f, 0.f};
            c = __builtin_amdgcn_mfma_f32_16x16x32_bf16(a0, qb0, c, 0, 0, 0);
            c = __builtin_amdgcn_mfma_f32_16x16x32_bf16(a1, qb1, c, 0, 0, 0);
            float4 vs = *(const float4*)(vsb + et * 16 + quad * 4);
            float m0 = asf(me[et].x << 16), m1 = asf(me[et].x & 0xffff0000u);
            float m2 = asf(me[et].y << 16), m3 = asf(me[et].y & 0xffff0000u);
            float v0 = 0.5f * (c[0] + vs.x) / dn + 0.5f * m0;
            float v1 = 0.5f * (c[1] + vs.y) / dn + 0.5f * m1;
            float v2 = 0.5f * (c[2] + vs.z) / dn + 0.5f * m2;
            float v3 = 0.5f * (c[3] + vs.w) / dn + 0.5f * m3;
            if (live) {
                uint2 st = make_uint2(pack2(v0, v1), pack2(v2, v3));
                *(uint2*)(curB + (size_t)n * 128 + h * 64 + et * 16 + quad * 4) = st;
            }
        }
    }
}

// ---- GCN gather + combine. Wave owns 2 nodes; quarter-groups 0-1 iterate
// node A's edges (stride 2), groups 2-3 node B's. ONE accumulator g[8]/lane,
// reduce = single shfl_xor(16) over the parity pair, parity-split uint2 write.
__global__ __launch_bounds__(256) void k_gcn(
    const unsigned short* __restrict__ curA,
    const int* __restrict__ rowstart, const int4* __restrict__ csr_pack,
    unsigned short* __restrict__ curB, unsigned short* __restrict__ acc, int N, int first)
{
    // bijective XCD swizzle (m204)
    int orig = blockIdx.x, nwg = gridDim.x;
    int q8 = nwg >> 3, r8 = nwg & 7;
    int xcd = orig & 7, jj = orig >> 3;
    int swz = (xcd < r8 ? xcd * (q8 + 1) : r8 * (q8 + 1) + (xcd - r8) * q8) + jj;

    int w = threadIdx.x >> 6, l = threadIdx.x & 63;
    int qq = l >> 4, ql = l & 15;
    int half = qq >> 1;          // 0 -> node A, 1 -> node B
    int par  = qq & 1;           // parity within the node's edge list
    int nA = swz * 8 + w * 2;
    if (nA >= N) return;
    bool hasB = (nA + 1) < N;
    int myN = nA + half;
    bool live = myN < N;
    int s0  = rowstart[nA];
    int sA1 = rowstart[nA + 1];
    int s1  = hasB ? rowstart[nA + 2] : sA1;
    int base = half ? sA1 : s0;
    int lim  = half ? s1  : sA1;

    // hoisted epilogue loads (this lane owns elements e0..e0+3 of myN)
    int e0 = 8 * ql + par * 4;
    size_t o = (size_t)myN * 128 + e0;
    const unsigned short* accsrc = first ? curA : acc;
    uint2 ub = make_uint2(0, 0), ua = make_uint2(0, 0);
    if (live) {
        ub = *(const uint2*)(curB + o);
        ua = *(const uint2*)(accsrc + o);
    }

    float g[8];
    #pragma unroll
    for (int j = 0; j < 8; ++j) g[j] = 0.f;
    const int2* cw2 = (const int2*)csr_pack;   // record stride 16B; take {col,w}
    #pragma unroll 2
    for (int i = base + par; i < lim; i += 2) {
        int2 cw = cw2[2 * i];
        float wv = __int_as_float(cw.y);
        uint4 u = *(const uint4*)(curA + (size_t)cw.x * 128 + 8 * ql);
        g[0] += wv * asf(u.x << 16); g[1] += wv * asf(u.x & 0xffff0000u);
        g[2] += wv * asf(u.y << 16); g[3] += wv * asf(u.y & 0xffff0000u);
        g[4] += wv * asf(u.z << 16); g[5] += wv * asf(u.z & 0xffff0000u);
        g[6] += wv * asf(u.w << 16); g[7] += wv * asf(u.w & 0xffff0000u);
    }
    // combine the two parity groups of this node (lanes differ by XOR 16)
    #pragma unroll
    for (int j = 0; j < 8; ++j) g[j] += __shfl_xor(g[j], 16, 64);
    // parity split: par=0 writes elems e0..e0+3 = 8*ql+0..3, par=1 -> 8*ql+4..7
    float s0v = par ? g[4] : g[0];
    float s1v = par ? g[5] : g[1];
    float s2v = par ? g[6] : g[2];
    float s3v = par ? g[7] : g[3];
    if (live) {
        float v0 = 0.5f * s0v + asf(ub.x << 16);
        float v1 = 0.5f * s1v + asf(ub.x & 0xffff0000u);
        float v2 = 0.5f * s2v + asf(ub.y << 16);
        float v3 = 0.5f * s3v + asf(ub.y & 0xffff0000u);
        *(uint2*)(curB + o) = make_uint2(pack2(v0, v1), pack2(v2, v3));
        float a0 = asf(ua.x << 16) + v0, a1 = asf(ua.x & 0xffff0000u) + v1;
        float a2 = asf(ua.y << 16) + v2, a3 = asf(ua.y & 0xffff0000u) + v3;
        *(uint2*)(acc + o) = make_uint2(pack2(a0, a1), pack2(a2, a3));
    }
}

// ---- out = (acc @ Wo^T + b) / 2 via MFMA -----------------------------------
__global__ __launch_bounds__(256) void k_outm(
    const unsigned short* __restrict__ acc, const unsigned short* __restrict__ Wob,
    const float* __restrict__ Wo_b, float* __restrict__ out, int N)
{
    int w = threadIdx.x >> 6, l = threadIdx.x & 63;
    int six = l & 15, quad = l >> 4;
    int base = (blockIdx.x * 4 + w) * 16;
    if (base >= N) return;
    int n = base + six;
    int nc = min(n, N - 1);
    const unsigned short* ar = acc + (size_t)nc * 128;
    bf16x8 b0 = *(const bf16x8*)(ar + quad * 8);
    bf16x8 b1 = *(const bf16x8*)(ar + 32 + quad * 8);
    bf16x8 b2 = *(const bf16x8*)(ar + 64 + quad * 8);
    bf16x8 b3 = *(const bf16x8*)(ar + 96 + quad * 8);
    #pragma unroll
    for (int t = 0; t < 4; ++t) {
        const unsigned short* wr = Wob + (size_t)(t * 16 + six) * 128;
        bf16x8 a0 = *(const bf16x8*)(wr + quad * 8);
        bf16x8 a1 = *(const bf16x8*)(wr + 32 + quad * 8);
        bf16x8 a2 = *(const bf16x8*)(wr + 64 + quad * 8);
        bf16x8 a3 = *(const bf16x8*)(wr + 96 + quad * 8);
        f32x4v c = {0.f, 0.f, 0.f, 0.f};
        c = __builtin_amdgcn_mfma_f32_16x16x32_bf16(a0, b0, c, 0, 0, 0);
        c = __builtin_amdgcn_mfma_f32_16x16x32_bf16(a1, b1, c, 0, 0, 0);
        c = __builtin_amdgcn_mfma_f32_16x16x32_bf16(a2, b2, c, 0, 0, 0);
        c = __builtin_amdgcn_mfma_f32_16x16x32_bf16(a3, b3, c, 0, 0, 0);
        if (n < N) {
            float4 bias = *(const float4*)(Wo_b + t * 16 + quad * 4);
            float4 o4;
            o4.x = (c[0] + bias.x) * 0.5f;
            o4.y = (c[1] + bias.y) * 0.5f;
            o4.z = (c[2] + bias.z) * 0.5f;
            o4.w = (c[3] + bias.w) * 0.5f;
            *(float4*)(out + (size_t)n * 64 + t * 16 + quad * 4) = o4;
        }
    }
}

extern "C" void kernel_launch(void* const* d_in, const int* in_sizes, int n_in,
                              void* d_out, int out_size, void* d_ws, size_t ws_size,
                              hipStream_t stream) {
    const float* x    = (const float*)d_in[0];
    const float* Wq_w = (const float*)d_in[1];
    const float* Wq_b = (const float*)d_in[2];
    const float* Wk_w = (const float*)d_in[3];
    const float* Wk_b = (const float*)d_in[4];
    const float* Wo_w = (const float*)d_in[5];
    const float* Wo_b = (const float*)d_in[6];
    const float* bond = (const float*)d_in[7];
    const int*   eidx = (const int*)d_in[8];
    const int*   eattr= (const int*)d_in[9];
    const int*   nn   = (const int*)d_in[10];
    float* out = (float*)d_out;
    int N = in_sizes[0] / 64;
    int E = in_sizes[9] / 3;
    int B = in_sizes[10];

    char* p = (char*)d_ws;
    auto alloc = [&](size_t bytes) { char* r = p; p += (bytes + 255) & ~(size_t)255; return r; };
    unsigned short* q    = (unsigned short*)alloc((size_t)N * 128 * 2);
    unsigned short* kq   = (unsigned short*)alloc((size_t)N * 128 * 2);
    unsigned short* curA = (unsigned short*)alloc((size_t)N * 128 * 2);
    unsigned short* curB = (unsigned short*)alloc((size_t)N * 128 * 2);
    unsigned short* acc  = (unsigned short*)alloc((size_t)N * 128 * 2);
    int maxchunks = (N + CHUNK - 1) / CHUNK + B;
    int maxtiles  = (N + 15) / 16 + B;
    unsigned short* partKV = (unsigned short*)alloc((size_t)maxchunks * 8192 * 2);
    float* partVS = (float*)alloc((size_t)maxchunks * 128 * 4);
    float* partKS = (float*)alloc((size_t)maxchunks * 128 * 4);
    unsigned short* kvT_b = (unsigned short*)alloc((size_t)B * 2 * 64 * 64 * 2);
    float* vsum  = (float*)alloc((size_t)B * 128 * 4);
    float* ksum  = (float*)alloc((size_t)B * 128 * 4);
    float* denom = (float*)alloc((size_t)N * 2 * 4);
    float* dis   = (float*)alloc((size_t)N * 4);
    int* deg     = (int*)alloc((size_t)N * 4);
    int* rowstart= (int*)alloc((size_t)(N + 1) * 4);
    int* slot    = (int*)alloc((size_t)E * 4);
    int4* csr_pack = (int4*)alloc((size_t)E * 16);
    int* batch   = (int*)alloc((size_t)N * 4);
    int* ptr     = (int*)alloc((size_t)(B + 1) * 4);
    int* cptr    = (int*)alloc((size_t)(B + 1) * 4);
    int* tptr    = (int*)alloc((size_t)(B + 1) * 4);
    unsigned short* Wb = (unsigned short*)alloc(24576 * 2);
    int nb = (N + 255) / 256;
    int* bsum    = (int*)alloc((size_t)nb * 4);
    unsigned short* msgb = (unsigned short*)out;  // [N,64] bf16 aliased onto d_out; k_outm rewrites it last

    hipMemsetAsync(deg, 0, (size_t)N * 4, stream);

    k_ptr  <<<1, 64, 0, stream>>>(nn, ptr, cptr, tptr, B);
    k_batch<<<B, 256, 0, stream>>>(ptr, batch);
    k_wcvt <<<96, 256, 0, stream>>>(Wq_w, Wk_w, Wo_w, Wb);
    k_qkm  <<<(N + 63) / 64, 256, 0, stream>>>(x, Wb, Wq_b, Wk_b, q, kq, curA, N);
    k_deg  <<<(E + 255) / 256, 256, 0, stream>>>(eidx, deg, slot, E);
    k_scan1<<<nb, 256, 0, stream>>>(deg, rowstart, bsum, dis, N);
    k_scan2<<<1, 512, 0, stream>>>(bsum, nb);
    k_scan3<<<nb, 256, 0, stream>>>(rowstart, bsum, N, E);
    k_fill <<<(E + 255) / 256, 256, 0, stream>>>(eidx, dis, rowstart, slot, csr_pack, eattr, E);
    k_msg  <<<2048, 256, 0, stream>>>(rowstart, csr_pack, bond, msgb, N);
    k_ksump<<<maxchunks, 256, 0, stream>>>(kq, ptr, cptr, partKS, B);
    k_ksr  <<<B, 128, 0, stream>>>(partKS, cptr, ksum, B);
    k_denom<<<(N + 3) / 4, 256, 0, stream>>>(q, ksum, batch, nn, denom, N);

    int gcnblk = (N + 7) / 8;
    for (int it = 0; it < 4; ++it) {
        k_kvp <<<maxchunks, 256, 0, stream>>>(kq, curA, ptr, cptr, partKV, partVS, B);
        k_red <<<B * 4, 256, 0, stream>>>(partKV, partVS, cptr, kvT_b, vsum, B);
        k_attn<<<(maxtiles + 3) / 4, 256, 0, stream>>>(q, kvT_b, vsum, denom, ptr, tptr, msgb, curB, B);
        k_gcn <<<gcnblk, 256, 0, stream>>>(curA, rowstart, csr_pack, curB, acc, N, it == 0 ? 1 : 0);
        unsigned short* tmp = curA; curA = curB; curB = tmp;
    }
    k_outm<<<(N + 63) / 64, 256, 0, stream>>>(acc, Wb + 16384, Wo_b, out, N);
}

// Round 11
// 670.952 us; speedup vs baseline: 1.2045x; 1.2045x over previous
//
#include <hip/hip_runtime.h>
#include <hip/hip_bf16.h>

// GloAttnConv R22: k_kvp rewritten as MFMA GEMM. kvT[e][d] = sum_n v[n][e]k[n][d]
// is a 64x64 outer-product GEMM with K=nodes; scalar version was VALU-floor
// bound (~52 inst/node/lane, VALUBusy 50%, 44us, immune to CHUNK changes
// R19/R21). MFMA: per 32-node K-step per wave: 48 ushort loads (const-offset
// foldable) + 12 mfma (8 kv + 4 ones-B for vsum). Layout per verified k_qkm/
// k_attn conventions: A lane-six -> C row (=e), B lane-six -> C col (=d).
// Tail steps: wave-uniform slow path (v clamped, k/ones zeroed). CHUNK=128.
// Rest = R20 state (+ k_qkm bias loads vectorized).

typedef __attribute__((ext_vector_type(8))) short bf16x8;
typedef __attribute__((ext_vector_type(4))) float f32x4v;

#define CHUNK 128

__device__ __forceinline__ float asf(unsigned int u) { union { unsigned int i; float f; } v; v.i = u; return v.f; }
__device__ __forceinline__ float b2f_u(unsigned short u) { return asf((unsigned int)u << 16); }
__device__ __forceinline__ unsigned short f2b_u(float f) {
    __hip_bfloat16 h = __float2bfloat16(f);
    union { __hip_bfloat16 h; unsigned short u; } v; v.h = h; return v.u;
}
__device__ __forceinline__ unsigned int pack2(float a, float b) {
    return (unsigned int)f2b_u(a) | ((unsigned int)f2b_u(b) << 16);
}
__device__ __forceinline__ float wave_reduce_sum(float v) {
    #pragma unroll
    for (int off = 32; off > 0; off >>= 1) v += __shfl_xor(v, off, 64);
    return v;
}

// ---- graph bookkeeping: node ptr + chunk ptr + 16-tile ptr ------------------
__global__ void k_ptr(const int* __restrict__ nn, int* __restrict__ ptr,
                      int* __restrict__ cptr, int* __restrict__ tptr, int B) {
    if (threadIdx.x == 0 && blockIdx.x == 0) {
        int s = 0, c = 0, t = 0; ptr[0] = 0; cptr[0] = 0; tptr[0] = 0;
        for (int i = 0; i < B; ++i) {
            s += nn[i]; ptr[i + 1] = s;
            c += (nn[i] + CHUNK - 1) / CHUNK; cptr[i + 1] = c;
            t += (nn[i] + 15) / 16; tptr[i + 1] = t;
        }
    }
}

__global__ void k_batch(const int* __restrict__ ptr, int* __restrict__ batch) {
    int b = blockIdx.x;
    int s = ptr[b], e = ptr[b + 1];
    for (int i = s + threadIdx.x; i < e; i += blockDim.x) batch[i] = b;
}

// ---- W -> bf16 stacked: [0,8192)=Wq, [8192,16384)=Wk, [16384,24576)=Wo ------
__global__ void k_wcvt(const float* __restrict__ Wq_w, const float* __restrict__ Wk_w,
                       const float* __restrict__ Wo_w, unsigned short* __restrict__ Wb) {
    int i = blockIdx.x * 256 + threadIdx.x;
    if (i < 24576) {
        float v = (i < 8192) ? Wq_w[i] : ((i < 16384) ? Wk_w[i - 8192] : Wo_w[i - 16384]);
        Wb[i] = f2b_u(v);
    }
}

// ---- q/k projection via MFMA + L2-normalize; writes q, kq, curA ------------
__global__ __launch_bounds__(256) void k_qkm(
    const float* __restrict__ x, const unsigned short* __restrict__ Wb,
    const float* __restrict__ Wq_b, const float* __restrict__ Wk_b,
    unsigned short* __restrict__ q, unsigned short* __restrict__ kq,
    unsigned short* __restrict__ curA, int N)
{
    int w = threadIdx.x >> 6, l = threadIdx.x & 63;
    int six = l & 15, quad = l >> 4;
    int base = (blockIdx.x * 4 + w) * 16;
    if (base >= N) return;
    int n = base + six;
    int nc = min(n, N - 1);

    const float* xr = x + (size_t)nc * 64;
    float4 xa = *(const float4*)(xr + quad * 8);
    float4 xb = *(const float4*)(xr + quad * 8 + 4);
    float4 xc = *(const float4*)(xr + 32 + quad * 8);
    float4 xd = *(const float4*)(xr + 32 + quad * 8 + 4);
    union { bf16x8 v; unsigned int u[4]; } b0, b1;
    b0.u[0] = pack2(xa.x, xa.y); b0.u[1] = pack2(xa.z, xa.w);
    b0.u[2] = pack2(xb.x, xb.y); b0.u[3] = pack2(xb.z, xb.w);
    b1.u[0] = pack2(xc.x, xc.y); b1.u[1] = pack2(xc.z, xc.w);
    b1.u[2] = pack2(xd.x, xd.y); b1.u[3] = pack2(xd.z, xd.w);
    if (n < N) {
        unsigned short* cr = curA + (size_t)n * 128;
        *(uint4*)(cr + quad * 8)       = make_uint4(b0.u[0], b0.u[1], b0.u[2], b0.u[3]);
        *(uint4*)(cr + 32 + quad * 8)  = make_uint4(b1.u[0], b1.u[1], b1.u[2], b1.u[3]);
        *(uint4*)(cr + 64 + quad * 8)  = make_uint4(b0.u[0], b0.u[1], b0.u[2], b0.u[3]);
        *(uint4*)(cr + 96 + quad * 8)  = make_uint4(b1.u[0], b1.u[1], b1.u[2], b1.u[3]);
    }

    #pragma unroll
    for (int g = 0; g < 4; ++g) {
        f32x4v c[4];
        #pragma unroll
        for (int tt = 0; tt < 4; ++tt) {
            int t = g * 4 + tt;
            const unsigned short* wr = Wb + (size_t)(t * 16 + six) * 64;
            bf16x8 a0 = *(const bf16x8*)(wr + quad * 8);
            bf16x8 a1 = *(const bf16x8*)(wr + 32 + quad * 8);
            f32x4v cc = {0.f, 0.f, 0.f, 0.f};
            cc = __builtin_amdgcn_mfma_f32_16x16x32_bf16(a0, b0.v, cc, 0, 0, 0);
            cc = __builtin_amdgcn_mfma_f32_16x16x32_bf16(a1, b1.v, cc, 0, 0, 0);
            c[tt] = cc;
        }
        const float* bias = (g < 2) ? Wq_b : Wk_b;
        int cb = (g & 1) * 64 + quad * 4;
        float ss = 0.f;
        #pragma unroll
        for (int tt = 0; tt < 4; ++tt) {
            float4 bv = *(const float4*)(bias + cb + tt * 16);
            c[tt][0] += bv.x; c[tt][1] += bv.y; c[tt][2] += bv.z; c[tt][3] += bv.w;
            ss += c[tt][0] * c[tt][0] + c[tt][1] * c[tt][1]
                + c[tt][2] * c[tt][2] + c[tt][3] * c[tt][3];
        }
        ss += __shfl_xor(ss, 16, 64);
        ss += __shfl_xor(ss, 32, 64);
        float sc = rsqrtf(ss);
        if (n < N) {
            unsigned short* dst = ((g < 2) ? q : kq) + (size_t)n * 128;
            #pragma unroll
            for (int tt = 0; tt < 4; ++tt) {
                unsigned int u0 = pack2(c[tt][0] * sc, c[tt][1] * sc);
                unsigned int u1 = pack2(c[tt][2] * sc, c[tt][3] * sc);
                *(uint2*)(dst + cb + tt * 16) = make_uint2(u0, u1);
            }
        }
    }
}

// ---- degree + slot assignment (slot = this edge's index within its row) ----
__global__ void k_deg(const int* __restrict__ row, int* __restrict__ deg,
                      int* __restrict__ slot, int E) {
    int e = blockIdx.x * 256 + threadIdx.x;
    if (e < E) slot[e] = atomicAdd(&deg[row[e]], 1);
}

// ---- exclusive scan of deg -> rowstart (+ dis folded in) -------------------
__global__ void k_scan1(const int* __restrict__ deg, int* __restrict__ rowstart,
                        int* __restrict__ bsum, float* __restrict__ dis, int N) {
    __shared__ int sh[256];
    int t = threadIdx.x, n = blockIdx.x * 256 + t;
    int v = (n < N) ? deg[n] : 0;
    if (n < N) dis[n] = v > 0 ? rsqrtf((float)v) : 0.f;
    sh[t] = v; __syncthreads();
    #pragma unroll
    for (int off = 1; off < 256; off <<= 1) {
        int add = (t >= off) ? sh[t - off] : 0;
        __syncthreads();
        sh[t] += add;
        __syncthreads();
    }
    if (n < N) rowstart[n] = sh[t] - v;
    if (t == 255) bsum[blockIdx.x] = sh[255];
}

__global__ void k_scan2(int* __restrict__ bsum, int nb) {
    __shared__ int sh[512];
    __shared__ int carry;
    int t = threadIdx.x;
    if (t == 0) carry = 0;
    __syncthreads();
    for (int base = 0; base < nb; base += 512) {
        int idx = base + t;
        int v = (idx < nb) ? bsum[idx] : 0;
        sh[t] = v; __syncthreads();
        for (int off = 1; off < 512; off <<= 1) {
            int add = (t >= off) ? sh[t - off] : 0;
            __syncthreads();
            sh[t] += add;
            __syncthreads();
        }
        if (idx < nb) bsum[idx] = sh[t] - v + carry;
        __syncthreads();
        if (t == 0) carry += sh[511];
        __syncthreads();
    }
}

__global__ void k_scan3(int* __restrict__ rowstart, const int* __restrict__ bsum, int N, int E) {
    int n = blockIdx.x * 256 + threadIdx.x;
    if (n < N) rowstart[n] += bsum[blockIdx.x];
    if (n == 0) rowstart[N] = E;
}

// ---- CSR fill: NO atomic (slot precomputed), ONE int4 16B store per edge ---
__global__ void k_fill(const int* __restrict__ eidx, const float* __restrict__ dis,
                       const int* __restrict__ rowstart, const int* __restrict__ slot,
                       int4* __restrict__ csr_pack, const int* __restrict__ eattr, int E) {
    int e = blockIdx.x * 256 + threadIdx.x;
    if (e >= E) return;
    int r = eidx[e], c = eidx[E + e];
    float wv = dis[r] * dis[c];
    int a0 = eattr[e * 3 + 0], a1 = eattr[e * 3 + 1], a2 = eattr[e * 3 + 2];
    int idx = rowstart[r] + slot[e];
    int4 v;
    v.x = c;
    v.y = __float_as_int(wv);
    v.z = a0 | (a1 << 8) | (a2 << 16);
    v.w = 0;
    csr_pack[idx] = v;
}

// ---- msg_edge[n,64] in BF16; bond table in LDS, wave per node --------------
__global__ __launch_bounds__(256) void k_msg(
    const int* __restrict__ rowstart, const int4* __restrict__ csr_pack,
    const float* __restrict__ bond, unsigned short* __restrict__ msgb, int N) {
    __shared__ float bl[1536];
    int t = threadIdx.x, w = t >> 6, l = t & 63;
    for (int i = t; i < 1536; i += 256) bl[i] = bond[i];
    __syncthreads();
    for (int n = blockIdx.x * 4 + w; n < N; n += gridDim.x * 4) {
        int s0 = rowstart[n], s1 = rowstart[n + 1];
        float m = 0.f;
        #pragma unroll 4
        for (int i = s0; i < s1; ++i) {
            int4 pk = csr_pack[i];
            float wv = __int_as_float(pk.y);
            int att = pk.z;
            m += wv * (bl[(att & 255) * 64 + l] + bl[(8 + ((att >> 8) & 255)) * 64 + l]
                     + bl[(16 + (att >> 16)) * 64 + l]);
        }
        msgb[(size_t)n * 64 + l] = f2b_u(m);
    }
}

// ---- ksum stage 1: per-chunk partial (plain stores) ------------------------
__global__ __launch_bounds__(256) void k_ksump(
    const unsigned short* __restrict__ kq, const int* __restrict__ ptr,
    const int* __restrict__ cptr, float* __restrict__ partKS, int B)
{
    int cid = blockIdx.x;
    if (cid >= cptr[B]) return;
    int lo = 0, hi = B - 1;
    while (lo < hi) { int mid = (lo + hi + 1) >> 1; if (cptr[mid] <= cid) lo = mid; else hi = mid - 1; }
    int b = lo;
    int start = ptr[b] + (cid - cptr[b]) * CHUNK;
    int end = min(start + CHUNK, ptr[b + 1]);
    int t = threadIdx.x, r = t >> 7, col = t & 127;
    float a = 0.f;
    for (int n = start + r; n < end; n += 2)
        a += b2f_u(kq[(size_t)n * 128 + col]);
    __shared__ float sh[256];
    sh[t] = a;
    __syncthreads();
    if (t < 128) partKS[(size_t)cid * 128 + t] = sh[t] + sh[t + 128];
}

// ---- ksum stage 2: sum chunk partials per graph ----------------------------
__global__ __launch_bounds__(128) void k_ksr(
    const float* __restrict__ partKS, const int* __restrict__ cptr,
    float* __restrict__ ksum, int B)
{
    int b = blockIdx.x, t = threadIdx.x;
    float s = 0.f;
    int c0 = cptr[b], c1 = cptr[b + 1];
    for (int c = c0; c < c1; ++c) s += partKS[(size_t)c * 128 + t];
    ksum[b * 128 + t] = s;
}

// ---- denom[n][h] = q[n,h,:].ksum[b,h,:] + n_nodes[b] -----------------------
__global__ __launch_bounds__(256) void k_denom(
    const unsigned short* __restrict__ q, const float* __restrict__ ksum,
    const int* __restrict__ batch, const int* __restrict__ nn,
    float* __restrict__ denom, int N)
{
    int w = threadIdx.x >> 6, l = threadIdx.x & 63;
    int n = blockIdx.x * 4 + w;
    if (n >= N) return;
    int b = batch[n];
    float d0 = b2f_u(q[(size_t)n * 128 + l]) * ksum[b * 128 + l];
    float d1 = b2f_u(q[(size_t)n * 128 + 64 + l]) * ksum[b * 128 + 64 + l];
    d0 = wave_reduce_sum(d0);
    d1 = wave_reduce_sum(d1);
    if (l == 0) {
        float nf = (float)nn[b];
        denom[n * 2 + 0] = d0 + nf;
        denom[n * 2 + 1] = d1 + nf;
    }
}

// ---- stage 1: per-chunk kv via MFMA. Wave = (h, dhalf). Per 32-node K-step:
// A[e][node] = v (lane six -> e), B[d][node] = k (lane six -> d), 8 kv-MFMA +
// 4 ones-B MFMA (vsum). Tail steps: wave-uniform slow path. ------------------
__global__ __launch_bounds__(256) void k_kvp(
    const unsigned short* __restrict__ kq, const unsigned short* __restrict__ cur,
    const int* __restrict__ ptr, const int* __restrict__ cptr,
    unsigned short* __restrict__ partKV, float* __restrict__ partVS, int B)
{
    int cid = blockIdx.x;
    if (cid >= cptr[B]) return;
    int lo = 0, hi = B - 1;
    while (lo < hi) { int mid = (lo + hi + 1) >> 1; if (cptr[mid] <= cid) lo = mid; else hi = mid - 1; }
    int b = lo;
    int start = ptr[b] + (cid - cptr[b]) * CHUNK;
    int end = min(start + CHUNK, ptr[b + 1]);

    int w = threadIdx.x >> 6, l = threadIdx.x & 63;
    int h = w >> 1, dhalf = w & 1;
    int six = l & 15, quad = l >> 4;

    f32x4v c00 = {0,0,0,0}, c01 = {0,0,0,0}, c10 = {0,0,0,0}, c11 = {0,0,0,0};
    f32x4v c20 = {0,0,0,0}, c21 = {0,0,0,0}, c30 = {0,0,0,0}, c31 = {0,0,0,0};
    f32x4v s0 = {0,0,0,0}, s1 = {0,0,0,0}, s2 = {0,0,0,0}, s3 = {0,0,0,0};

    const unsigned short ONE = 0x3F80;  // bf16 1.0

    for (int nb = start; nb < end; nb += 32) {
        union { bf16x8 v; unsigned short s[8]; } a0u, a1u, a2u, a3u, b0u, b1u, onu;
        if (nb + 32 <= end) {
            // fast path: constant-stride loads (offsets fold into immediates)
            const unsigned short* vb = cur + (size_t)(nb + quad * 8) * 128 + h * 64 + six;
            const unsigned short* kb = kq  + (size_t)(nb + quad * 8) * 128 + h * 64 + dhalf * 32 + six;
            #pragma unroll
            for (int j = 0; j < 8; ++j) {
                a0u.s[j] = vb[j * 128];
                a1u.s[j] = vb[j * 128 + 16];
                a2u.s[j] = vb[j * 128 + 32];
                a3u.s[j] = vb[j * 128 + 48];
                b0u.s[j] = kb[j * 128];
                b1u.s[j] = kb[j * 128 + 16];
                onu.s[j] = ONE;
            }
        } else {
            #pragma unroll
            for (int j = 0; j < 8; ++j) {
                int nd = nb + quad * 8 + j;
                int ndc = min(nd, end - 1);
                bool ok = nd < end;
                const unsigned short* vb = cur + (size_t)ndc * 128 + h * 64 + six;
                const unsigned short* kb = kq  + (size_t)ndc * 128 + h * 64 + dhalf * 32 + six;
                a0u.s[j] = vb[0];
                a1u.s[j] = vb[16];
                a2u.s[j] = vb[32];
                a3u.s[j] = vb[48];
                b0u.s[j] = ok ? kb[0]  : (unsigned short)0;
                b1u.s[j] = ok ? kb[16] : (unsigned short)0;
                onu.s[j] = ok ? ONE : (unsigned short)0;
            }
        }
        c00 = __builtin_amdgcn_mfma_f32_16x16x32_bf16(a0u.v, b0u.v, c00, 0, 0, 0);
        c01 = __builtin_amdgcn_mfma_f32_16x16x32_bf16(a0u.v, b1u.v, c01, 0, 0, 0);
        c10 = __builtin_amdgcn_mfma_f32_16x16x32_bf16(a1u.v, b0u.v, c10, 0, 0, 0);
        c11 = __builtin_amdgcn_mfma_f32_16x16x32_bf16(a1u.v, b1u.v, c11, 0, 0, 0);
        c20 = __builtin_amdgcn_mfma_f32_16x16x32_bf16(a2u.v, b0u.v, c20, 0, 0, 0);
        c21 = __builtin_amdgcn_mfma_f32_16x16x32_bf16(a2u.v, b1u.v, c21, 0, 0, 0);
        c30 = __builtin_amdgcn_mfma_f32_16x16x32_bf16(a3u.v, b0u.v, c30, 0, 0, 0);
        c31 = __builtin_amdgcn_mfma_f32_16x16x32_bf16(a3u.v, b1u.v, c31, 0, 0, 0);
        s0  = __builtin_amdgcn_mfma_f32_16x16x32_bf16(a0u.v, onu.v, s0, 0, 0, 0);
        s1  = __builtin_amdgcn_mfma_f32_16x16x32_bf16(a1u.v, onu.v, s1, 0, 0, 0);
        s2  = __builtin_amdgcn_mfma_f32_16x16x32_bf16(a2u.v, onu.v, s2, 0, 0, 0);
        s3  = __builtin_amdgcn_mfma_f32_16x16x32_bf16(a3u.v, onu.v, s3, 0, 0, 0);
    }

    // write partKV[cid][h*4096 + e*64 + d]: e = et*16 + quad*4 + r, d = dhalf*32 + dt*16 + six
    unsigned short* dst = partKV + (size_t)cid * 8192 + h * 4096 + dhalf * 32 + six;
    #pragma unroll
    for (int r = 0; r < 4; ++r) {
        int e = quad * 4 + r;
        dst[(e +  0) * 64 +  0] = f2b_u(c00[r]);
        dst[(e +  0) * 64 + 16] = f2b_u(c01[r]);
        dst[(e + 16) * 64 +  0] = f2b_u(c10[r]);
        dst[(e + 16) * 64 + 16] = f2b_u(c11[r]);
        dst[(e + 32) * 64 +  0] = f2b_u(c20[r]);
        dst[(e + 32) * 64 + 16] = f2b_u(c21[r]);
        dst[(e + 48) * 64 +  0] = f2b_u(c30[r]);
        dst[(e + 48) * 64 + 16] = f2b_u(c31[r]);
    }
    if (dhalf == 0 && six == 0) {
        float* vdst = partVS + (size_t)cid * 128 + h * 64;
        #pragma unroll
        for (int r = 0; r < 4; ++r) {
            int e = quad * 4 + r;
            vdst[e]      = s0[r];
            vdst[e + 16] = s1[r];
            vdst[e + 32] = s2[r];
            vdst[e + 48] = s3[r];
        }
    }
}

// ---- stage 2: sum bf16 partials -> kvT bf16 + vsum (256 blocks) ------------
__global__ __launch_bounds__(256) void k_red(
    const unsigned short* __restrict__ partKV, const float* __restrict__ partVS,
    const int* __restrict__ cptr, unsigned short* __restrict__ kvT_b,
    float* __restrict__ vsum, int B)
{
    int bid = blockIdx.x;
    int gh = bid >> 1, half = bid & 1;
    int g = gh >> 1, h = gh & 1;
    int c0 = cptr[g], c1 = cptr[g + 1];
    int t = threadIdx.x;
    int off = half * 2048 + t * 8;   // element offset within the 4096-elem strip
    float s[8];
    #pragma unroll
    for (int i = 0; i < 8; ++i) s[i] = 0.f;
    for (int c = c0; c < c1; ++c) {
        uint4 u = *(const uint4*)(partKV + (size_t)c * 8192 + h * 4096 + off);
        s[0] += asf(u.x << 16); s[1] += asf(u.x & 0xffff0000u);
        s[2] += asf(u.y << 16); s[3] += asf(u.y & 0xffff0000u);
        s[4] += asf(u.z << 16); s[5] += asf(u.z & 0xffff0000u);
        s[6] += asf(u.w << 16); s[7] += asf(u.w & 0xffff0000u);
    }
    unsigned int u[4];
    #pragma unroll
    for (int i = 0; i < 4; ++i) u[i] = pack2(s[2 * i], s[2 * i + 1]);
    *(uint4*)(kvT_b + (size_t)gh * 4096 + off) = make_uint4(u[0], u[1], u[2], u[3]);
    if (half == 0 && t < 64) {
        float vs = 0.f;
        for (int c = c0; c < c1; ++c) vs += partVS[(size_t)c * 128 + h * 64 + t];
        vsum[g * 128 + h * 64 + t] = vs;
    }
}

// ---- attn via MFMA on graph-aligned 16-node tiles; also adds 0.5*msg -------
__global__ __launch_bounds__(256) void k_attn(
    const unsigned short* __restrict__ q, const unsigned short* __restrict__ kvT,
    const float* __restrict__ vsum, const float* __restrict__ denom,
    const int* __restrict__ ptr, const int* __restrict__ tptr,
    const unsigned short* __restrict__ msgb,
    unsigned short* __restrict__ curB, int B)
{
    int w = threadIdx.x >> 6, l = threadIdx.x & 63;
    int tid = blockIdx.x * 4 + w;
    if (tid >= tptr[B]) return;
    int lo = 0, hi = B - 1;
    while (lo < hi) { int mid = (lo + hi + 1) >> 1; if (tptr[mid] <= tid) lo = mid; else hi = mid - 1; }
    int b0 = lo;
    int start = ptr[b0] + (tid - tptr[b0]) * 16;
    int end = min(start + 16, ptr[b0 + 1]);
    int quad = l >> 4, six = l & 15;
    int n = start + six;        // this lane's node (C column)
    int nc = min(n, end - 1);   // clamped for loads
    bool live = n < end;
    const unsigned short* mrow = msgb + (size_t)nc * 64;
    uint2 me[4];
    #pragma unroll
    for (int et = 0; et < 4; ++et) me[et] = *(const uint2*)(mrow + et * 16 + quad * 4);
    #pragma unroll
    for (int h = 0; h < 2; ++h) {
        const unsigned short* qrow = q + (size_t)nc * 128 + h * 64;
        bf16x8 qb0 = *(const bf16x8*)(qrow + quad * 8);        // B-frag k=quad*8+j
        bf16x8 qb1 = *(const bf16x8*)(qrow + 32 + quad * 8);
        const unsigned short* Bb = kvT + (size_t)(b0 * 2 + h) * 4096;
        float dn = denom[nc * 2 + h];
        const float* vsb = vsum + (b0 * 2 + h) * 64;
        #pragma unroll
        for (int et = 0; et < 4; ++et) {
            const unsigned short* arow = Bb + (size_t)(et * 16 + six) * 64;  // A m=e row
            bf16x8 a0 = *(const bf16x8*)(arow + quad * 8);
            bf16x8 a1 = *(const bf16x8*)(arow + 32 + quad * 8);
            f32x4v c = {0.f, 0.f, 0.f, 0.f};
            c = __builtin_amdgcn_mfma_f32_16x16x32_bf16(a0, qb0, c, 0, 0, 0);
            c = __builtin_amdgcn_mfma_f32_16x16x32_bf16(a1, qb1, c, 0, 0, 0);
            float4 vs = *(const float4*)(vsb + et * 16 + quad * 4);
            float m0 = asf(me[et].x << 16), m1 = asf(me[et].x & 0xffff0000u);
            float m2 = asf(me[et].y << 16), m3 = asf(me[et].y & 0xffff0000u);
            float v0 = 0.5f * (c[0] + vs.x) / dn + 0.5f * m0;
            float v1 = 0.5f * (c[1] + vs.y) / dn + 0.5f * m1;
            float v2 = 0.5f * (c[2] + vs.z) / dn + 0.5f * m2;
            float v3 = 0.5f * (c[3] + vs.w) / dn + 0.5f * m3;
            if (live) {
                uint2 st = make_uint2(pack2(v0, v1), pack2(v2, v3));
                *(uint2*)(curB + (size_t)n * 128 + h * 64 + et * 16 + quad * 4) = st;
            }
        }
    }
}

// ---- GCN gather + combine. Wave owns 2 nodes; quarter-groups 0-1 iterate
// node A's edges (stride 2), groups 2-3 node B's. ONE accumulator g[8]/lane,
// reduce = single shfl_xor(16) over the parity pair, parity-split uint2 write.
__global__ __launch_bounds__(256) void k_gcn(
    const unsigned short* __restrict__ curA,
    const int* __restrict__ rowstart, const int4* __restrict__ csr_pack,
    unsigned short* __restrict__ curB, unsigned short* __restrict__ acc, int N, int first)
{
    // bijective XCD swizzle (m204)
    int orig = blockIdx.x, nwg = gridDim.x;
    int q8 = nwg >> 3, r8 = nwg & 7;
    int xcd = orig & 7, jj = orig >> 3;
    int swz = (xcd < r8 ? xcd * (q8 + 1) : r8 * (q8 + 1) + (xcd - r8) * q8) + jj;

    int w = threadIdx.x >> 6, l = threadIdx.x & 63;
    int qq = l >> 4, ql = l & 15;
    int half = qq >> 1;          // 0 -> node A, 1 -> node B
    int par  = qq & 1;           // parity within the node's edge list
    int nA = swz * 8 + w * 2;
    if (nA >= N) return;
    bool hasB = (nA + 1) < N;
    int myN = nA + half;
    bool live = myN < N;
    int s0  = rowstart[nA];
    int sA1 = rowstart[nA + 1];
    int s1  = hasB ? rowstart[nA + 2] : sA1;
    int base = half ? sA1 : s0;
    int lim  = half ? s1  : sA1;

    // hoisted epilogue loads (this lane owns elements e0..e0+3 of myN)
    int e0 = 8 * ql + par * 4;
    size_t o = (size_t)myN * 128 + e0;
    const unsigned short* accsrc = first ? curA : acc;
    uint2 ub = make_uint2(0, 0), ua = make_uint2(0, 0);
    if (live) {
        ub = *(const uint2*)(curB + o);
        ua = *(const uint2*)(accsrc + o);
    }

    float g[8];
    #pragma unroll
    for (int j = 0; j < 8; ++j) g[j] = 0.f;
    const int2* cw2 = (const int2*)csr_pack;   // record stride 16B; take {col,w}
    #pragma unroll 2
    for (int i = base + par; i < lim; i += 2) {
        int2 cw = cw2[2 * i];
        float wv = __int_as_float(cw.y);
        uint4 u = *(const uint4*)(curA + (size_t)cw.x * 128 + 8 * ql);
        g[0] += wv * asf(u.x << 16); g[1] += wv * asf(u.x & 0xffff0000u);
        g[2] += wv * asf(u.y << 16); g[3] += wv * asf(u.y & 0xffff0000u);
        g[4] += wv * asf(u.z << 16); g[5] += wv * asf(u.z & 0xffff0000u);
        g[6] += wv * asf(u.w << 16); g[7] += wv * asf(u.w & 0xffff0000u);
    }
    // combine the two parity groups of this node (lanes differ by XOR 16)
    #pragma unroll
    for (int j = 0; j < 8; ++j) g[j] += __shfl_xor(g[j], 16, 64);
    // parity split: par=0 writes elems e0..e0+3 = 8*ql+0..3, par=1 -> 8*ql+4..7
    float s0v = par ? g[4] : g[0];
    float s1v = par ? g[5] : g[1];
    float s2v = par ? g[6] : g[2];
    float s3v = par ? g[7] : g[3];
    if (live) {
        float v0 = 0.5f * s0v + asf(ub.x << 16);
        float v1 = 0.5f * s1v + asf(ub.x & 0xffff0000u);
        float v2 = 0.5f * s2v + asf(ub.y << 16);
        float v3 = 0.5f * s3v + asf(ub.y & 0xffff0000u);
        *(uint2*)(curB + o) = make_uint2(pack2(v0, v1), pack2(v2, v3));
        float a0 = asf(ua.x << 16) + v0, a1 = asf(ua.x & 0xffff0000u) + v1;
        float a2 = asf(ua.y << 16) + v2, a3 = asf(ua.y & 0xffff0000u) + v3;
        *(uint2*)(acc + o) = make_uint2(pack2(a0, a1), pack2(a2, a3));
    }
}

// ---- out = (acc @ Wo^T + b) / 2 via MFMA -----------------------------------
__global__ __launch_bounds__(256) void k_outm(
    const unsigned short* __restrict__ acc, const unsigned short* __restrict__ Wob,
    const float* __restrict__ Wo_b, float* __restrict__ out, int N)
{
    int w = threadIdx.x >> 6, l = threadIdx.x & 63;
    int six = l & 15, quad = l >> 4;
    int base = (blockIdx.x * 4 + w) * 16;
    if (base >= N) return;
    int n = base + six;
    int nc = min(n, N - 1);
    const unsigned short* ar = acc + (size_t)nc * 128;
    bf16x8 b0 = *(const bf16x8*)(ar + quad * 8);
    bf16x8 b1 = *(const bf16x8*)(ar + 32 + quad * 8);
    bf16x8 b2 = *(const bf16x8*)(ar + 64 + quad * 8);
    bf16x8 b3 = *(const bf16x8*)(ar + 96 + quad * 8);
    #pragma unroll
    for (int t = 0; t < 4; ++t) {
        const unsigned short* wr = Wob + (size_t)(t * 16 + six) * 128;
        bf16x8 a0 = *(const bf16x8*)(wr + quad * 8);
        bf16x8 a1 = *(const bf16x8*)(wr + 32 + quad * 8);
        bf16x8 a2 = *(const bf16x8*)(wr + 64 + quad * 8);
        bf16x8 a3 = *(const bf16x8*)(wr + 96 + quad * 8);
        f32x4v c = {0.f, 0.f, 0.f, 0.f};
        c = __builtin_amdgcn_mfma_f32_16x16x32_bf16(a0, b0, c, 0, 0, 0);
        c = __builtin_amdgcn_mfma_f32_16x16x32_bf16(a1, b1, c, 0, 0, 0);
        c = __builtin_amdgcn_mfma_f32_16x16x32_bf16(a2, b2, c, 0, 0, 0);
        c = __builtin_amdgcn_mfma_f32_16x16x32_bf16(a3, b3, c, 0, 0, 0);
        if (n < N) {
            float4 bias = *(const float4*)(Wo_b + t * 16 + quad * 4);
            float4 o4;
            o4.x = (c[0] + bias.x) * 0.5f;
            o4.y = (c[1] + bias.y) * 0.5f;
            o4.z = (c[2] + bias.z) * 0.5f;
            o4.w = (c[3] + bias.w) * 0.5f;
            *(float4*)(out + (size_t)n * 64 + t * 16 + quad * 4) = o4;
        }
    }
}

extern "C" void kernel_launch(void* const* d_in, const int* in_sizes, int n_in,
                              void* d_out, int out_size, void* d_ws, size_t ws_size,
                              hipStream_t stream) {
    const float* x    = (const float*)d_in[0];
    const float* Wq_w = (const float*)d_in[1];
    const float* Wq_b = (const float*)d_in[2];
    const float* Wk_w = (const float*)d_in[3];
    const float* Wk_b = (const float*)d_in[4];
    const float* Wo_w = (const float*)d_in[5];
    const float* Wo_b = (const float*)d_in[6];
    const float* bond = (const float*)d_in[7];
    const int*   eidx = (const int*)d_in[8];
    const int*   eattr= (const int*)d_in[9];
    const int*   nn   = (const int*)d_in[10];
    float* out = (float*)d_out;
    int N = in_sizes[0] / 64;
    int E = in_sizes[9] / 3;
    int B = in_sizes[10];

    char* p = (char*)d_ws;
    auto alloc = [&](size_t bytes) { char* r = p; p += (bytes + 255) & ~(size_t)255; return r; };
    unsigned short* q    = (unsigned short*)alloc((size_t)N * 128 * 2);
    unsigned short* kq   = (unsigned short*)alloc((size_t)N * 128 * 2);
    unsigned short* curA = (unsigned short*)alloc((size_t)N * 128 * 2);
    unsigned short* curB = (unsigned short*)alloc((size_t)N * 128 * 2);
    unsigned short* acc  = (unsigned short*)alloc((size_t)N * 128 * 2);
    int maxchunks = (N + CHUNK - 1) / CHUNK + B;
    int maxtiles  = (N + 15) / 16 + B;
    unsigned short* partKV = (unsigned short*)alloc((size_t)maxchunks * 8192 * 2);
    float* partVS = (float*)alloc((size_t)maxchunks * 128 * 4);
    float* partKS = (float*)alloc((size_t)maxchunks * 128 * 4);
    unsigned short* kvT_b = (unsigned short*)alloc((size_t)B * 2 * 64 * 64 * 2);
    float* vsum  = (float*)alloc((size_t)B * 128 * 4);
    float* ksum  = (float*)alloc((size_t)B * 128 * 4);
    float* denom = (float*)alloc((size_t)N * 2 * 4);
    float* dis   = (float*)alloc((size_t)N * 4);
    int* deg     = (int*)alloc((size_t)N * 4);
    int* rowstart= (int*)alloc((size_t)(N + 1) * 4);
    int* slot    = (int*)alloc((size_t)E * 4);
    int4* csr_pack = (int4*)alloc((size_t)E * 16);
    int* batch   = (int*)alloc((size_t)N * 4);
    int* ptr     = (int*)alloc((size_t)(B + 1) * 4);
    int* cptr    = (int*)alloc((size_t)(B + 1) * 4);
    int* tptr    = (int*)alloc((size_t)(B + 1) * 4);
    unsigned short* Wb = (unsigned short*)alloc(24576 * 2);
    int nb = (N + 255) / 256;
    int* bsum    = (int*)alloc((size_t)nb * 4);
    unsigned short* msgb = (unsigned short*)out;  // [N,64] bf16 aliased onto d_out; k_outm rewrites it last

    hipMemsetAsync(deg, 0, (size_t)N * 4, stream);

    k_ptr  <<<1, 64, 0, stream>>>(nn, ptr, cptr, tptr, B);
    k_batch<<<B, 256, 0, stream>>>(ptr, batch);
    k_wcvt <<<96, 256, 0, stream>>>(Wq_w, Wk_w, Wo_w, Wb);
    k_qkm  <<<(N + 63) / 64, 256, 0, stream>>>(x, Wb, Wq_b, Wk_b, q, kq, curA, N);
    k_deg  <<<(E + 255) / 256, 256, 0, stream>>>(eidx, deg, slot, E);
    k_scan1<<<nb, 256, 0, stream>>>(deg, rowstart, bsum, dis, N);
    k_scan2<<<1, 512, 0, stream>>>(bsum, nb);
    k_scan3<<<nb, 256, 0, stream>>>(rowstart, bsum, N, E);
    k_fill <<<(E + 255) / 256, 256, 0, stream>>>(eidx, dis, rowstart, slot, csr_pack, eattr, E);
    k_msg  <<<2048, 256, 0, stream>>>(rowstart, csr_pack, bond, msgb, N);
    k_ksump<<<maxchunks, 256, 0, stream>>>(kq, ptr, cptr, partKS, B);
    k_ksr  <<<B, 128, 0, stream>>>(partKS, cptr, ksum, B);
    k_denom<<<(N + 3) / 4, 256, 0, stream>>>(q, ksum, batch, nn, denom, N);

    int gcnblk = (N + 7) / 8;
    for (int it = 0; it < 4; ++it) {
        k_kvp <<<maxchunks, 256, 0, stream>>>(kq, curA, ptr, cptr, partKV, partVS, B);
        k_red <<<B * 4, 256, 0, stream>>>(partKV, partVS, cptr, kvT_b, vsum, B);
        k_attn<<<(maxtiles + 3) / 4, 256, 0, stream>>>(q, kvT_b, vsum, denom, ptr, tptr, msgb, curB, B);
        k_gcn <<<gcnblk, 256, 0, stream>>>(curA, rowstart, csr_pack, curB, acc, N, it == 0 ? 1 : 0);
        unsigned short* tmp = curA; curA = curB; curB = tmp;
    }
    k_outm<<<(N + 63) / 64, 256, 0, stream>>>(acc, Wb + 16384, Wo_b, out, N);
}

// Round 12
// 668.505 us; speedup vs baseline: 1.2089x; 1.0037x over previous
//
#include <hip/hip_runtime.h>
#include <hip/hip_bf16.h>

// GloAttnConv R23: k_qkm coalesced writes via per-wave LDS staging. The MFMA
// C-layout puts node n in lane 'six', so direct stores are 16B at stride 256B
// (16 discontiguous segments per store inst) -> k_qkm was 44us at VALUBusy 10%
// / 2 TB/s: store-pipe bound. Now each wave stages its 16x64 tile in LDS
// (stride-72 rows, ~2-way bank alias = free) and flushes with contiguous 16B
// stores (8 lanes = 128B half-row). Per-wave buffer + wave_barrier only (no
// syncthreads; early-return safe). Rest = R22 (MFMA k_kvp etc.) unchanged.

typedef __attribute__((ext_vector_type(8))) short bf16x8;
typedef __attribute__((ext_vector_type(4))) float f32x4v;

#define CHUNK 128

__device__ __forceinline__ float asf(unsigned int u) { union { unsigned int i; float f; } v; v.i = u; return v.f; }
__device__ __forceinline__ float b2f_u(unsigned short u) { return asf((unsigned int)u << 16); }
__device__ __forceinline__ unsigned short f2b_u(float f) {
    __hip_bfloat16 h = __float2bfloat16(f);
    union { __hip_bfloat16 h; unsigned short u; } v; v.h = h; return v.u;
}
__device__ __forceinline__ unsigned int pack2(float a, float b) {
    return (unsigned int)f2b_u(a) | ((unsigned int)f2b_u(b) << 16);
}
__device__ __forceinline__ float wave_reduce_sum(float v) {
    #pragma unroll
    for (int off = 32; off > 0; off >>= 1) v += __shfl_xor(v, off, 64);
    return v;
}

// ---- graph bookkeeping: node ptr + chunk ptr + 16-tile ptr ------------------
__global__ void k_ptr(const int* __restrict__ nn, int* __restrict__ ptr,
                      int* __restrict__ cptr, int* __restrict__ tptr, int B) {
    if (threadIdx.x == 0 && blockIdx.x == 0) {
        int s = 0, c = 0, t = 0; ptr[0] = 0; cptr[0] = 0; tptr[0] = 0;
        for (int i = 0; i < B; ++i) {
            s += nn[i]; ptr[i + 1] = s;
            c += (nn[i] + CHUNK - 1) / CHUNK; cptr[i + 1] = c;
            t += (nn[i] + 15) / 16; tptr[i + 1] = t;
        }
    }
}

__global__ void k_batch(const int* __restrict__ ptr, int* __restrict__ batch) {
    int b = blockIdx.x;
    int s = ptr[b], e = ptr[b + 1];
    for (int i = s + threadIdx.x; i < e; i += blockDim.x) batch[i] = b;
}

// ---- W -> bf16 stacked: [0,8192)=Wq, [8192,16384)=Wk, [16384,24576)=Wo ------
__global__ void k_wcvt(const float* __restrict__ Wq_w, const float* __restrict__ Wk_w,
                       const float* __restrict__ Wo_w, unsigned short* __restrict__ Wb) {
    int i = blockIdx.x * 256 + threadIdx.x;
    if (i < 24576) {
        float v = (i < 8192) ? Wq_w[i] : ((i < 16384) ? Wk_w[i - 8192] : Wo_w[i - 16384]);
        Wb[i] = f2b_u(v);
    }
}

// ---- q/k projection via MFMA + L2-normalize; LDS-staged coalesced writes ---
__global__ __launch_bounds__(256) void k_qkm(
    const float* __restrict__ x, const unsigned short* __restrict__ Wb,
    const float* __restrict__ Wq_b, const float* __restrict__ Wk_b,
    unsigned short* __restrict__ q, unsigned short* __restrict__ kq,
    unsigned short* __restrict__ curA, int N)
{
    __shared__ unsigned short sbuf[4][16][72];   // per-wave 16x64 tile, stride 72
    int w = threadIdx.x >> 6, l = threadIdx.x & 63;
    int six = l & 15, quad = l >> 4;
    int base = (blockIdx.x * 4 + w) * 16;
    if (base >= N) return;
    int n = base + six;
    int nc = min(n, N - 1);
    int r0 = l >> 3, m = l & 7;

    const float* xr = x + (size_t)nc * 64;
    float4 xa = *(const float4*)(xr + quad * 8);
    float4 xb = *(const float4*)(xr + quad * 8 + 4);
    float4 xc = *(const float4*)(xr + 32 + quad * 8);
    float4 xd = *(const float4*)(xr + 32 + quad * 8 + 4);
    union { bf16x8 v; unsigned int u[4]; } b0, b1;
    b0.u[0] = pack2(xa.x, xa.y); b0.u[1] = pack2(xa.z, xa.w);
    b0.u[2] = pack2(xb.x, xb.y); b0.u[3] = pack2(xb.z, xb.w);
    b1.u[0] = pack2(xc.x, xc.y); b1.u[1] = pack2(xc.z, xc.w);
    b1.u[2] = pack2(xd.x, xd.y); b1.u[3] = pack2(xd.z, xd.w);

    // stage x-tile (64 cols) and flush to BOTH curA halves, coalesced
    *(uint4*)&sbuf[w][six][quad * 8]      = make_uint4(b0.u[0], b0.u[1], b0.u[2], b0.u[3]);
    *(uint4*)&sbuf[w][six][32 + quad * 8] = make_uint4(b1.u[0], b1.u[1], b1.u[2], b1.u[3]);
    __builtin_amdgcn_wave_barrier();
    #pragma unroll
    for (int c = 0; c < 2; ++c) {
        int r = r0 + c * 8;
        int n2 = base + r;
        if (n2 < N) {
            uint4 d = *(const uint4*)&sbuf[w][r][m * 8];
            unsigned short* cr = curA + (size_t)n2 * 128 + m * 8;
            *(uint4*)cr = d;
            *(uint4*)(cr + 64) = d;
        }
    }
    __builtin_amdgcn_wave_barrier();

    #pragma unroll
    for (int g = 0; g < 4; ++g) {
        f32x4v c[4];
        #pragma unroll
        for (int tt = 0; tt < 4; ++tt) {
            int t = g * 4 + tt;
            const unsigned short* wr = Wb + (size_t)(t * 16 + six) * 64;
            bf16x8 a0 = *(const bf16x8*)(wr + quad * 8);
            bf16x8 a1 = *(const bf16x8*)(wr + 32 + quad * 8);
            f32x4v cc = {0.f, 0.f, 0.f, 0.f};
            cc = __builtin_amdgcn_mfma_f32_16x16x32_bf16(a0, b0.v, cc, 0, 0, 0);
            cc = __builtin_amdgcn_mfma_f32_16x16x32_bf16(a1, b1.v, cc, 0, 0, 0);
            c[tt] = cc;
        }
        const float* bias = (g < 2) ? Wq_b : Wk_b;
        int cb = (g & 1) * 64 + quad * 4;
        float ss = 0.f;
        #pragma unroll
        for (int tt = 0; tt < 4; ++tt) {
            float4 bv = *(const float4*)(bias + cb + tt * 16);
            c[tt][0] += bv.x; c[tt][1] += bv.y; c[tt][2] += bv.z; c[tt][3] += bv.w;
            ss += c[tt][0] * c[tt][0] + c[tt][1] * c[tt][1]
                + c[tt][2] * c[tt][2] + c[tt][3] * c[tt][3];
        }
        ss += __shfl_xor(ss, 16, 64);
        ss += __shfl_xor(ss, 32, 64);
        float sc = rsqrtf(ss);
        // stage this 64-col half into LDS, then flush coalesced
        #pragma unroll
        for (int tt = 0; tt < 4; ++tt) {
            unsigned int u0 = pack2(c[tt][0] * sc, c[tt][1] * sc);
            unsigned int u1 = pack2(c[tt][2] * sc, c[tt][3] * sc);
            *(uint2*)&sbuf[w][six][tt * 16 + quad * 4] = make_uint2(u0, u1);
        }
        __builtin_amdgcn_wave_barrier();
        unsigned short* arr = (g < 2) ? q : kq;
        #pragma unroll
        for (int c2 = 0; c2 < 2; ++c2) {
            int r = r0 + c2 * 8;
            int n2 = base + r;
            if (n2 < N)
                *(uint4*)(arr + (size_t)n2 * 128 + (g & 1) * 64 + m * 8)
                    = *(const uint4*)&sbuf[w][r][m * 8];
        }
        __builtin_amdgcn_wave_barrier();
    }
}

// ---- degree + slot assignment (slot = this edge's index within its row) ----
__global__ void k_deg(const int* __restrict__ row, int* __restrict__ deg,
                      int* __restrict__ slot, int E) {
    int e = blockIdx.x * 256 + threadIdx.x;
    if (e < E) slot[e] = atomicAdd(&deg[row[e]], 1);
}

// ---- exclusive scan of deg -> rowstart (+ dis folded in) -------------------
__global__ void k_scan1(const int* __restrict__ deg, int* __restrict__ rowstart,
                        int* __restrict__ bsum, float* __restrict__ dis, int N) {
    __shared__ int sh[256];
    int t = threadIdx.x, n = blockIdx.x * 256 + t;
    int v = (n < N) ? deg[n] : 0;
    if (n < N) dis[n] = v > 0 ? rsqrtf((float)v) : 0.f;
    sh[t] = v; __syncthreads();
    #pragma unroll
    for (int off = 1; off < 256; off <<= 1) {
        int add = (t >= off) ? sh[t - off] : 0;
        __syncthreads();
        sh[t] += add;
        __syncthreads();
    }
    if (n < N) rowstart[n] = sh[t] - v;
    if (t == 255) bsum[blockIdx.x] = sh[255];
}

__global__ void k_scan2(int* __restrict__ bsum, int nb) {
    __shared__ int sh[512];
    __shared__ int carry;
    int t = threadIdx.x;
    if (t == 0) carry = 0;
    __syncthreads();
    for (int base = 0; base < nb; base += 512) {
        int idx = base + t;
        int v = (idx < nb) ? bsum[idx] : 0;
        sh[t] = v; __syncthreads();
        for (int off = 1; off < 512; off <<= 1) {
            int add = (t >= off) ? sh[t - off] : 0;
            __syncthreads();
            sh[t] += add;
            __syncthreads();
        }
        if (idx < nb) bsum[idx] = sh[t] - v + carry;
        __syncthreads();
        if (t == 0) carry += sh[511];
        __syncthreads();
    }
}

__global__ void k_scan3(int* __restrict__ rowstart, const int* __restrict__ bsum, int N, int E) {
    int n = blockIdx.x * 256 + threadIdx.x;
    if (n < N) rowstart[n] += bsum[blockIdx.x];
    if (n == 0) rowstart[N] = E;
}

// ---- CSR fill: NO atomic (slot precomputed), ONE int4 16B store per edge ---
__global__ void k_fill(const int* __restrict__ eidx, const float* __restrict__ dis,
                       const int* __restrict__ rowstart, const int* __restrict__ slot,
                       int4* __restrict__ csr_pack, const int* __restrict__ eattr, int E) {
    int e = blockIdx.x * 256 + threadIdx.x;
    if (e >= E) return;
    int r = eidx[e], c = eidx[E + e];
    float wv = dis[r] * dis[c];
    int a0 = eattr[e * 3 + 0], a1 = eattr[e * 3 + 1], a2 = eattr[e * 3 + 2];
    int idx = rowstart[r] + slot[e];
    int4 v;
    v.x = c;
    v.y = __float_as_int(wv);
    v.z = a0 | (a1 << 8) | (a2 << 16);
    v.w = 0;
    csr_pack[idx] = v;
}

// ---- msg_edge[n,64] in BF16; bond table in LDS, wave per node --------------
__global__ __launch_bounds__(256) void k_msg(
    const int* __restrict__ rowstart, const int4* __restrict__ csr_pack,
    const float* __restrict__ bond, unsigned short* __restrict__ msgb, int N) {
    __shared__ float bl[1536];
    int t = threadIdx.x, w = t >> 6, l = t & 63;
    for (int i = t; i < 1536; i += 256) bl[i] = bond[i];
    __syncthreads();
    for (int n = blockIdx.x * 4 + w; n < N; n += gridDim.x * 4) {
        int s0 = rowstart[n], s1 = rowstart[n + 1];
        float m = 0.f;
        #pragma unroll 4
        for (int i = s0; i < s1; ++i) {
            int4 pk = csr_pack[i];
            float wv = __int_as_float(pk.y);
            int att = pk.z;
            m += wv * (bl[(att & 255) * 64 + l] + bl[(8 + ((att >> 8) & 255)) * 64 + l]
                     + bl[(16 + (att >> 16)) * 64 + l]);
        }
        msgb[(size_t)n * 64 + l] = f2b_u(m);
    }
}

// ---- ksum stage 1: per-chunk partial (plain stores) ------------------------
__global__ __launch_bounds__(256) void k_ksump(
    const unsigned short* __restrict__ kq, const int* __restrict__ ptr,
    const int* __restrict__ cptr, float* __restrict__ partKS, int B)
{
    int cid = blockIdx.x;
    if (cid >= cptr[B]) return;
    int lo = 0, hi = B - 1;
    while (lo < hi) { int mid = (lo + hi + 1) >> 1; if (cptr[mid] <= cid) lo = mid; else hi = mid - 1; }
    int b = lo;
    int start = ptr[b] + (cid - cptr[b]) * CHUNK;
    int end = min(start + CHUNK, ptr[b + 1]);
    int t = threadIdx.x, r = t >> 7, col = t & 127;
    float a = 0.f;
    for (int n = start + r; n < end; n += 2)
        a += b2f_u(kq[(size_t)n * 128 + col]);
    __shared__ float sh[256];
    sh[t] = a;
    __syncthreads();
    if (t < 128) partKS[(size_t)cid * 128 + t] = sh[t] + sh[t + 128];
}

// ---- ksum stage 2: sum chunk partials per graph ----------------------------
__global__ __launch_bounds__(128) void k_ksr(
    const float* __restrict__ partKS, const int* __restrict__ cptr,
    float* __restrict__ ksum, int B)
{
    int b = blockIdx.x, t = threadIdx.x;
    float s = 0.f;
    int c0 = cptr[b], c1 = cptr[b + 1];
    for (int c = c0; c < c1; ++c) s += partKS[(size_t)c * 128 + t];
    ksum[b * 128 + t] = s;
}

// ---- denom[n][h] = q[n,h,:].ksum[b,h,:] + n_nodes[b] -----------------------
__global__ __launch_bounds__(256) void k_denom(
    const unsigned short* __restrict__ q, const float* __restrict__ ksum,
    const int* __restrict__ batch, const int* __restrict__ nn,
    float* __restrict__ denom, int N)
{
    int w = threadIdx.x >> 6, l = threadIdx.x & 63;
    int n = blockIdx.x * 4 + w;
    if (n >= N) return;
    int b = batch[n];
    float d0 = b2f_u(q[(size_t)n * 128 + l]) * ksum[b * 128 + l];
    float d1 = b2f_u(q[(size_t)n * 128 + 64 + l]) * ksum[b * 128 + 64 + l];
    d0 = wave_reduce_sum(d0);
    d1 = wave_reduce_sum(d1);
    if (l == 0) {
        float nf = (float)nn[b];
        denom[n * 2 + 0] = d0 + nf;
        denom[n * 2 + 1] = d1 + nf;
    }
}

// ---- stage 1: per-chunk kv via MFMA (R22, verified) ------------------------
__global__ __launch_bounds__(256) void k_kvp(
    const unsigned short* __restrict__ kq, const unsigned short* __restrict__ cur,
    const int* __restrict__ ptr, const int* __restrict__ cptr,
    unsigned short* __restrict__ partKV, float* __restrict__ partVS, int B)
{
    int cid = blockIdx.x;
    if (cid >= cptr[B]) return;
    int lo = 0, hi = B - 1;
    while (lo < hi) { int mid = (lo + hi + 1) >> 1; if (cptr[mid] <= cid) lo = mid; else hi = mid - 1; }
    int b = lo;
    int start = ptr[b] + (cid - cptr[b]) * CHUNK;
    int end = min(start + CHUNK, ptr[b + 1]);

    int w = threadIdx.x >> 6, l = threadIdx.x & 63;
    int h = w >> 1, dhalf = w & 1;
    int six = l & 15, quad = l >> 4;

    f32x4v c00 = {0,0,0,0}, c01 = {0,0,0,0}, c10 = {0,0,0,0}, c11 = {0,0,0,0};
    f32x4v c20 = {0,0,0,0}, c21 = {0,0,0,0}, c30 = {0,0,0,0}, c31 = {0,0,0,0};
    f32x4v s0 = {0,0,0,0}, s1 = {0,0,0,0}, s2 = {0,0,0,0}, s3 = {0,0,0,0};

    const unsigned short ONE = 0x3F80;  // bf16 1.0

    for (int nb = start; nb < end; nb += 32) {
        union { bf16x8 v; unsigned short s[8]; } a0u, a1u, a2u, a3u, b0u, b1u, onu;
        if (nb + 32 <= end) {
            const unsigned short* vb = cur + (size_t)(nb + quad * 8) * 128 + h * 64 + six;
            const unsigned short* kb = kq  + (size_t)(nb + quad * 8) * 128 + h * 64 + dhalf * 32 + six;
            #pragma unroll
            for (int j = 0; j < 8; ++j) {
                a0u.s[j] = vb[j * 128];
                a1u.s[j] = vb[j * 128 + 16];
                a2u.s[j] = vb[j * 128 + 32];
                a3u.s[j] = vb[j * 128 + 48];
                b0u.s[j] = kb[j * 128];
                b1u.s[j] = kb[j * 128 + 16];
                onu.s[j] = ONE;
            }
        } else {
            #pragma unroll
            for (int j = 0; j < 8; ++j) {
                int nd = nb + quad * 8 + j;
                int ndc = min(nd, end - 1);
                bool ok = nd < end;
                const unsigned short* vb = cur + (size_t)ndc * 128 + h * 64 + six;
                const unsigned short* kb = kq  + (size_t)ndc * 128 + h * 64 + dhalf * 32 + six;
                a0u.s[j] = vb[0];
                a1u.s[j] = vb[16];
                a2u.s[j] = vb[32];
                a3u.s[j] = vb[48];
                b0u.s[j] = ok ? kb[0]  : (unsigned short)0;
                b1u.s[j] = ok ? kb[16] : (unsigned short)0;
                onu.s[j] = ok ? ONE : (unsigned short)0;
            }
        }
        c00 = __builtin_amdgcn_mfma_f32_16x16x32_bf16(a0u.v, b0u.v, c00, 0, 0, 0);
        c01 = __builtin_amdgcn_mfma_f32_16x16x32_bf16(a0u.v, b1u.v, c01, 0, 0, 0);
        c10 = __builtin_amdgcn_mfma_f32_16x16x32_bf16(a1u.v, b0u.v, c10, 0, 0, 0);
        c11 = __builtin_amdgcn_mfma_f32_16x16x32_bf16(a1u.v, b1u.v, c11, 0, 0, 0);
        c20 = __builtin_amdgcn_mfma_f32_16x16x32_bf16(a2u.v, b0u.v, c20, 0, 0, 0);
        c21 = __builtin_amdgcn_mfma_f32_16x16x32_bf16(a2u.v, b1u.v, c21, 0, 0, 0);
        c30 = __builtin_amdgcn_mfma_f32_16x16x32_bf16(a3u.v, b0u.v, c30, 0, 0, 0);
        c31 = __builtin_amdgcn_mfma_f32_16x16x32_bf16(a3u.v, b1u.v, c31, 0, 0, 0);
        s0  = __builtin_amdgcn_mfma_f32_16x16x32_bf16(a0u.v, onu.v, s0, 0, 0, 0);
        s1  = __builtin_amdgcn_mfma_f32_16x16x32_bf16(a1u.v, onu.v, s1, 0, 0, 0);
        s2  = __builtin_amdgcn_mfma_f32_16x16x32_bf16(a2u.v, onu.v, s2, 0, 0, 0);
        s3  = __builtin_amdgcn_mfma_f32_16x16x32_bf16(a3u.v, onu.v, s3, 0, 0, 0);
    }

    unsigned short* dst = partKV + (size_t)cid * 8192 + h * 4096 + dhalf * 32 + six;
    #pragma unroll
    for (int r = 0; r < 4; ++r) {
        int e = quad * 4 + r;
        dst[(e +  0) * 64 +  0] = f2b_u(c00[r]);
        dst[(e +  0) * 64 + 16] = f2b_u(c01[r]);
        dst[(e + 16) * 64 +  0] = f2b_u(c10[r]);
        dst[(e + 16) * 64 + 16] = f2b_u(c11[r]);
        dst[(e + 32) * 64 +  0] = f2b_u(c20[r]);
        dst[(e + 32) * 64 + 16] = f2b_u(c21[r]);
        dst[(e + 48) * 64 +  0] = f2b_u(c30[r]);
        dst[(e + 48) * 64 + 16] = f2b_u(c31[r]);
    }
    if (dhalf == 0 && six == 0) {
        float* vdst = partVS + (size_t)cid * 128 + h * 64;
        #pragma unroll
        for (int r = 0; r < 4; ++r) {
            int e = quad * 4 + r;
            vdst[e]      = s0[r];
            vdst[e + 16] = s1[r];
            vdst[e + 32] = s2[r];
            vdst[e + 48] = s3[r];
        }
    }
}

// ---- stage 2: sum bf16 partials -> kvT bf16 + vsum (256 blocks) ------------
__global__ __launch_bounds__(256) void k_red(
    const unsigned short* __restrict__ partKV, const float* __restrict__ partVS,
    const int* __restrict__ cptr, unsigned short* __restrict__ kvT_b,
    float* __restrict__ vsum, int B)
{
    int bid = blockIdx.x;
    int gh = bid >> 1, half = bid & 1;
    int g = gh >> 1, h = gh & 1;
    int c0 = cptr[g], c1 = cptr[g + 1];
    int t = threadIdx.x;
    int off = half * 2048 + t * 8;   // element offset within the 4096-elem strip
    float s[8];
    #pragma unroll
    for (int i = 0; i < 8; ++i) s[i] = 0.f;
    for (int c = c0; c < c1; ++c) {
        uint4 u = *(const uint4*)(partKV + (size_t)c * 8192 + h * 4096 + off);
        s[0] += asf(u.x << 16); s[1] += asf(u.x & 0xffff0000u);
        s[2] += asf(u.y << 16); s[3] += asf(u.y & 0xffff0000u);
        s[4] += asf(u.z << 16); s[5] += asf(u.z & 0xffff0000u);
        s[6] += asf(u.w << 16); s[7] += asf(u.w & 0xffff0000u);
    }
    unsigned int u[4];
    #pragma unroll
    for (int i = 0; i < 4; ++i) u[i] = pack2(s[2 * i], s[2 * i + 1]);
    *(uint4*)(kvT_b + (size_t)gh * 4096 + off) = make_uint4(u[0], u[1], u[2], u[3]);
    if (half == 0 && t < 64) {
        float vs = 0.f;
        for (int c = c0; c < c1; ++c) vs += partVS[(size_t)c * 128 + h * 64 + t];
        vsum[g * 128 + h * 64 + t] = vs;
    }
}

// ---- attn via MFMA on graph-aligned 16-node tiles; also adds 0.5*msg -------
__global__ __launch_bounds__(256) void k_attn(
    const unsigned short* __restrict__ q, const unsigned short* __restrict__ kvT,
    const float* __restrict__ vsum, const float* __restrict__ denom,
    const int* __restrict__ ptr, const int* __restrict__ tptr,
    const unsigned short* __restrict__ msgb,
    unsigned short* __restrict__ curB, int B)
{
    int w = threadIdx.x >> 6, l = threadIdx.x & 63;
    int tid = blockIdx.x * 4 + w;
    if (tid >= tptr[B]) return;
    int lo = 0, hi = B - 1;
    while (lo < hi) { int mid = (lo + hi + 1) >> 1; if (tptr[mid] <= tid) lo = mid; else hi = mid - 1; }
    int b0 = lo;
    int start = ptr[b0] + (tid - tptr[b0]) * 16;
    int end = min(start + 16, ptr[b0 + 1]);
    int quad = l >> 4, six = l & 15;
    int n = start + six;        // this lane's node (C column)
    int nc = min(n, end - 1);   // clamped for loads
    bool live = n < end;
    const unsigned short* mrow = msgb + (size_t)nc * 64;
    uint2 me[4];
    #pragma unroll
    for (int et = 0; et < 4; ++et) me[et] = *(const uint2*)(mrow + et * 16 + quad * 4);
    #pragma unroll
    for (int h = 0; h < 2; ++h) {
        const unsigned short* qrow = q + (size_t)nc * 128 + h * 64;
        bf16x8 qb0 = *(const bf16x8*)(qrow + quad * 8);        // B-frag k=quad*8+j
        bf16x8 qb1 = *(const bf16x8*)(qrow + 32 + quad * 8);
        const unsigned short* Bb = kvT + (size_t)(b0 * 2 + h) * 4096;
        float dn = denom[nc * 2 + h];
        const float* vsb = vsum + (b0 * 2 + h) * 64;
        #pragma unroll
        for (int et = 0; et < 4; ++et) {
            const unsigned short* arow = Bb + (size_t)(et * 16 + six) * 64;  // A m=e row
            bf16x8 a0 = *(const bf16x8*)(arow + quad * 8);
            bf16x8 a1 = *(const bf16x8*)(arow + 32 + quad * 8);
            f32x4v c = {0.f, 0.f, 0.f, 0.f};
            c = __builtin_amdgcn_mfma_f32_16x16x32_bf16(a0, qb0, c, 0, 0, 0);
            c = __builtin_amdgcn_mfma_f32_16x16x32_bf16(a1, qb1, c, 0, 0, 0);
            float4 vs = *(const float4*)(vsb + et * 16 + quad * 4);
            float m0 = asf(me[et].x << 16), m1 = asf(me[et].x & 0xffff0000u);
            float m2 = asf(me[et].y << 16), m3 = asf(me[et].y & 0xffff0000u);
            float v0 = 0.5f * (c[0] + vs.x) / dn + 0.5f * m0;
            float v1 = 0.5f * (c[1] + vs.y) / dn + 0.5f * m1;
            float v2 = 0.5f * (c[2] + vs.z) / dn + 0.5f * m2;
            float v3 = 0.5f * (c[3] + vs.w) / dn + 0.5f * m3;
            if (live) {
                uint2 st = make_uint2(pack2(v0, v1), pack2(v2, v3));
                *(uint2*)(curB + (size_t)n * 128 + h * 64 + et * 16 + quad * 4) = st;
            }
        }
    }
}

// ---- GCN gather + combine (R19 group-per-node form, verified) --------------
__global__ __launch_bounds__(256) void k_gcn(
    const unsigned short* __restrict__ curA,
    const int* __restrict__ rowstart, const int4* __restrict__ csr_pack,
    unsigned short* __restrict__ curB, unsigned short* __restrict__ acc, int N, int first)
{
    // bijective XCD swizzle (m204)
    int orig = blockIdx.x, nwg = gridDim.x;
    int q8 = nwg >> 3, r8 = nwg & 7;
    int xcd = orig & 7, jj = orig >> 3;
    int swz = (xcd < r8 ? xcd * (q8 + 1) : r8 * (q8 + 1) + (xcd - r8) * q8) + jj;

    int w = threadIdx.x >> 6, l = threadIdx.x & 63;
    int qq = l >> 4, ql = l & 15;
    int half = qq >> 1;          // 0 -> node A, 1 -> node B
    int par  = qq & 1;           // parity within the node's edge list
    int nA = swz * 8 + w * 2;
    if (nA >= N) return;
    bool hasB = (nA + 1) < N;
    int myN = nA + half;
    bool live = myN < N;
    int s0  = rowstart[nA];
    int sA1 = rowstart[nA + 1];
    int s1  = hasB ? rowstart[nA + 2] : sA1;
    int base = half ? sA1 : s0;
    int lim  = half ? s1  : sA1;

    int e0 = 8 * ql + par * 4;
    size_t o = (size_t)myN * 128 + e0;
    const unsigned short* accsrc = first ? curA : acc;
    uint2 ub = make_uint2(0, 0), ua = make_uint2(0, 0);
    if (live) {
        ub = *(const uint2*)(curB + o);
        ua = *(const uint2*)(accsrc + o);
    }

    float g[8];
    #pragma unroll
    for (int j = 0; j < 8; ++j) g[j] = 0.f;
    const int2* cw2 = (const int2*)csr_pack;   // record stride 16B; take {col,w}
    #pragma unroll 2
    for (int i = base + par; i < lim; i += 2) {
        int2 cw = cw2[2 * i];
        float wv = __int_as_float(cw.y);
        uint4 u = *(const uint4*)(curA + (size_t)cw.x * 128 + 8 * ql);
        g[0] += wv * asf(u.x << 16); g[1] += wv * asf(u.x & 0xffff0000u);
        g[2] += wv * asf(u.y << 16); g[3] += wv * asf(u.y & 0xffff0000u);
        g[4] += wv * asf(u.z << 16); g[5] += wv * asf(u.z & 0xffff0000u);
        g[6] += wv * asf(u.w << 16); g[7] += wv * asf(u.w & 0xffff0000u);
    }
    #pragma unroll
    for (int j = 0; j < 8; ++j) g[j] += __shfl_xor(g[j], 16, 64);
    float s0v = par ? g[4] : g[0];
    float s1v = par ? g[5] : g[1];
    float s2v = par ? g[6] : g[2];
    float s3v = par ? g[7] : g[3];
    if (live) {
        float v0 = 0.5f * s0v + asf(ub.x << 16);
        float v1 = 0.5f * s1v + asf(ub.x & 0xffff0000u);
        float v2 = 0.5f * s2v + asf(ub.y << 16);
        float v3 = 0.5f * s3v + asf(ub.y & 0xffff0000u);
        *(uint2*)(curB + o) = make_uint2(pack2(v0, v1), pack2(v2, v3));
        float a0 = asf(ua.x << 16) + v0, a1 = asf(ua.x & 0xffff0000u) + v1;
        float a2 = asf(ua.y << 16) + v2, a3 = asf(ua.y & 0xffff0000u) + v3;
        *(uint2*)(acc + o) = make_uint2(pack2(a0, a1), pack2(a2, a3));
    }
}

// ---- out = (acc @ Wo^T + b) / 2 via MFMA -----------------------------------
__global__ __launch_bounds__(256) void k_outm(
    const unsigned short* __restrict__ acc, const unsigned short* __restrict__ Wob,
    const float* __restrict__ Wo_b, float* __restrict__ out, int N)
{
    int w = threadIdx.x >> 6, l = threadIdx.x & 63;
    int six = l & 15, quad = l >> 4;
    int base = (blockIdx.x * 4 + w) * 16;
    if (base >= N) return;
    int n = base + six;
    int nc = min(n, N - 1);
    const unsigned short* ar = acc + (size_t)nc * 128;
    bf16x8 b0 = *(const bf16x8*)(ar + quad * 8);
    bf16x8 b1 = *(const bf16x8*)(ar + 32 + quad * 8);
    bf16x8 b2 = *(const bf16x8*)(ar + 64 + quad * 8);
    bf16x8 b3 = *(const bf16x8*)(ar + 96 + quad * 8);
    #pragma unroll
    for (int t = 0; t < 4; ++t) {
        const unsigned short* wr = Wob + (size_t)(t * 16 + six) * 128;
        bf16x8 a0 = *(const bf16x8*)(wr + quad * 8);
        bf16x8 a1 = *(const bf16x8*)(wr + 32 + quad * 8);
        bf16x8 a2 = *(const bf16x8*)(wr + 64 + quad * 8);
        bf16x8 a3 = *(const bf16x8*)(wr + 96 + quad * 8);
        f32x4v c = {0.f, 0.f, 0.f, 0.f};
        c = __builtin_amdgcn_mfma_f32_16x16x32_bf16(a0, b0, c, 0, 0, 0);
        c = __builtin_amdgcn_mfma_f32_16x16x32_bf16(a1, b1, c, 0, 0, 0);
        c = __builtin_amdgcn_mfma_f32_16x16x32_bf16(a2, b2, c, 0, 0, 0);
        c = __builtin_amdgcn_mfma_f32_16x16x32_bf16(a3, b3, c, 0, 0, 0);
        if (n < N) {
            float4 bias = *(const float4*)(Wo_b + t * 16 + quad * 4);
            float4 o4;
            o4.x = (c[0] + bias.x) * 0.5f;
            o4.y = (c[1] + bias.y) * 0.5f;
            o4.z = (c[2] + bias.z) * 0.5f;
            o4.w = (c[3] + bias.w) * 0.5f;
            *(float4*)(out + (size_t)n * 64 + t * 16 + quad * 4) = o4;
        }
    }
}

extern "C" void kernel_launch(void* const* d_in, const int* in_sizes, int n_in,
                              void* d_out, int out_size, void* d_ws, size_t ws_size,
                              hipStream_t stream) {
    const float* x    = (const float*)d_in[0];
    const float* Wq_w = (const float*)d_in[1];
    const float* Wq_b = (const float*)d_in[2];
    const float* Wk_w = (const float*)d_in[3];
    const float* Wk_b = (const float*)d_in[4];
    const float* Wo_w = (const float*)d_in[5];
    const float* Wo_b = (const float*)d_in[6];
    const float* bond = (const float*)d_in[7];
    const int*   eidx = (const int*)d_in[8];
    const int*   eattr= (const int*)d_in[9];
    const int*   nn   = (const int*)d_in[10];
    float* out = (float*)d_out;
    int N = in_sizes[0] / 64;
    int E = in_sizes[9] / 3;
    int B = in_sizes[10];

    char* p = (char*)d_ws;
    auto alloc = [&](size_t bytes) { char* r = p; p += (bytes + 255) & ~(size_t)255; return r; };
    unsigned short* q    = (unsigned short*)alloc((size_t)N * 128 * 2);
    unsigned short* kq   = (unsigned short*)alloc((size_t)N * 128 * 2);
    unsigned short* curA = (unsigned short*)alloc((size_t)N * 128 * 2);
    unsigned short* curB = (unsigned short*)alloc((size_t)N * 128 * 2);
    unsigned short* acc  = (unsigned short*)alloc((size_t)N * 128 * 2);
    int maxchunks = (N + CHUNK - 1) / CHUNK + B;
    int maxtiles  = (N + 15) / 16 + B;
    unsigned short* partKV = (unsigned short*)alloc((size_t)maxchunks * 8192 * 2);
    float* partVS = (float*)alloc((size_t)maxchunks * 128 * 4);
    float* partKS = (float*)alloc((size_t)maxchunks * 128 * 4);
    unsigned short* kvT_b = (unsigned short*)alloc((size_t)B * 2 * 64 * 64 * 2);
    float* vsum  = (float*)alloc((size_t)B * 128 * 4);
    float* ksum  = (float*)alloc((size_t)B * 128 * 4);
    float* denom = (float*)alloc((size_t)N * 2 * 4);
    float* dis   = (float*)alloc((size_t)N * 4);
    int* deg     = (int*)alloc((size_t)N * 4);
    int* rowstart= (int*)alloc((size_t)(N + 1) * 4);
    int* slot    = (int*)alloc((size_t)E * 4);
    int4* csr_pack = (int4*)alloc((size_t)E * 16);
    int* batch   = (int*)alloc((size_t)N * 4);
    int* ptr     = (int*)alloc((size_t)(B + 1) * 4);
    int* cptr    = (int*)alloc((size_t)(B + 1) * 4);
    int* tptr    = (int*)alloc((size_t)(B + 1) * 4);
    unsigned short* Wb = (unsigned short*)alloc(24576 * 2);
    int nb = (N + 255) / 256;
    int* bsum    = (int*)alloc((size_t)nb * 4);
    unsigned short* msgb = (unsigned short*)out;  // [N,64] bf16 aliased onto d_out; k_outm rewrites it last

    hipMemsetAsync(deg, 0, (size_t)N * 4, stream);

    k_ptr  <<<1, 64, 0, stream>>>(nn, ptr, cptr, tptr, B);
    k_batch<<<B, 256, 0, stream>>>(ptr, batch);
    k_wcvt <<<96, 256, 0, stream>>>(Wq_w, Wk_w, Wo_w, Wb);
    k_qkm  <<<(N + 63) / 64, 256, 0, stream>>>(x, Wb, Wq_b, Wk_b, q, kq, curA, N);
    k_deg  <<<(E + 255) / 256, 256, 0, stream>>>(eidx, deg, slot, E);
    k_scan1<<<nb, 256, 0, stream>>>(deg, rowstart, bsum, dis, N);
    k_scan2<<<1, 512, 0, stream>>>(bsum, nb);
    k_scan3<<<nb, 256, 0, stream>>>(rowstart, bsum, N, E);
    k_fill <<<(E + 255) / 256, 256, 0, stream>>>(eidx, dis, rowstart, slot, csr_pack, eattr, E);
    k_msg  <<<2048, 256, 0, stream>>>(rowstart, csr_pack, bond, msgb, N);
    k_ksump<<<maxchunks, 256, 0, stream>>>(kq, ptr, cptr, partKS, B);
    k_ksr  <<<B, 128, 0, stream>>>(partKS, cptr, ksum, B);
    k_denom<<<(N + 3) / 4, 256, 0, stream>>>(q, ksum, batch, nn, denom, N);

    int gcnblk = (N + 7) / 8;
    for (int it = 0; it < 4; ++it) {
        k_kvp <<<maxchunks, 256, 0, stream>>>(kq, curA, ptr, cptr, partKV, partVS, B);
        k_red <<<B * 4, 256, 0, stream>>>(partKV, partVS, cptr, kvT_b, vsum, B);
        k_attn<<<(maxtiles + 3) / 4, 256, 0, stream>>>(q, kvT_b, vsum, denom, ptr, tptr, msgb, curB, B);
        k_gcn <<<gcnblk, 256, 0, stream>>>(curA, rowstart, csr_pack, curB, acc, N, it == 0 ? 1 : 0);
        unsigned short* tmp = curA; curA = curB; curB = tmp;
    }
    k_outm<<<(N + 63) / 64, 256, 0, stream>>>(acc, Wb + 16384, Wo_b, out, N);
}

// Round 13
// 662.875 us; speedup vs baseline: 1.2192x; 1.0085x over previous
//
#include <hip/hip_runtime.h>
#include <hip/hip_bf16.h>

// GloAttnConv R24: deduplicate iteration-0 features. curA's two 64-wide halves
// were identical (h = broadcast x), yet written/streamed/gathered at 128-wide.
// Now k_qkm writes x0[N][64] (12.3MB, -17% of its writes); it=0 k_kvp reads
// pitch=64/hoff=0; it=0 k_gcn gathers a 12.3MB working set -> ~1.5MB/XCD with
// the swizzle = L2-resident (tests the R15 mechanism at a size that fits).
// pitch/hoff are wave-uniform params; acc-init reads x0[(e0&63)]. curB is
// fully overwritten by k_attn each iter before any read, so the swap chain
// stays valid. R23's k_qkm LDS staging kept (neutral), rest unchanged.

typedef __attribute__((ext_vector_type(8))) short bf16x8;
typedef __attribute__((ext_vector_type(4))) float f32x4v;

#define CHUNK 128

__device__ __forceinline__ float asf(unsigned int u) { union { unsigned int i; float f; } v; v.i = u; return v.f; }
__device__ __forceinline__ float b2f_u(unsigned short u) { return asf((unsigned int)u << 16); }
__device__ __forceinline__ unsigned short f2b_u(float f) {
    __hip_bfloat16 h = __float2bfloat16(f);
    union { __hip_bfloat16 h; unsigned short u; } v; v.h = h; return v.u;
}
__device__ __forceinline__ unsigned int pack2(float a, float b) {
    return (unsigned int)f2b_u(a) | ((unsigned int)f2b_u(b) << 16);
}
__device__ __forceinline__ float wave_reduce_sum(float v) {
    #pragma unroll
    for (int off = 32; off > 0; off >>= 1) v += __shfl_xor(v, off, 64);
    return v;
}

// ---- graph bookkeeping: node ptr + chunk ptr + 16-tile ptr ------------------
__global__ void k_ptr(const int* __restrict__ nn, int* __restrict__ ptr,
                      int* __restrict__ cptr, int* __restrict__ tptr, int B) {
    if (threadIdx.x == 0 && blockIdx.x == 0) {
        int s = 0, c = 0, t = 0; ptr[0] = 0; cptr[0] = 0; tptr[0] = 0;
        for (int i = 0; i < B; ++i) {
            s += nn[i]; ptr[i + 1] = s;
            c += (nn[i] + CHUNK - 1) / CHUNK; cptr[i + 1] = c;
            t += (nn[i] + 15) / 16; tptr[i + 1] = t;
        }
    }
}

__global__ void k_batch(const int* __restrict__ ptr, int* __restrict__ batch) {
    int b = blockIdx.x;
    int s = ptr[b], e = ptr[b + 1];
    for (int i = s + threadIdx.x; i < e; i += blockDim.x) batch[i] = b;
}

// ---- W -> bf16 stacked: [0,8192)=Wq, [8192,16384)=Wk, [16384,24576)=Wo ------
__global__ void k_wcvt(const float* __restrict__ Wq_w, const float* __restrict__ Wk_w,
                       const float* __restrict__ Wo_w, unsigned short* __restrict__ Wb) {
    int i = blockIdx.x * 256 + threadIdx.x;
    if (i < 24576) {
        float v = (i < 8192) ? Wq_w[i] : ((i < 16384) ? Wk_w[i - 8192] : Wo_w[i - 16384]);
        Wb[i] = f2b_u(v);
    }
}

// ---- q/k projection via MFMA + L2-normalize; writes q, kq, x0[N][64] -------
__global__ __launch_bounds__(256) void k_qkm(
    const float* __restrict__ x, const unsigned short* __restrict__ Wb,
    const float* __restrict__ Wq_b, const float* __restrict__ Wk_b,
    unsigned short* __restrict__ q, unsigned short* __restrict__ kq,
    unsigned short* __restrict__ x0, int N)
{
    __shared__ unsigned short sbuf[4][16][72];   // per-wave 16x64 tile, stride 72
    int w = threadIdx.x >> 6, l = threadIdx.x & 63;
    int six = l & 15, quad = l >> 4;
    int base = (blockIdx.x * 4 + w) * 16;
    if (base >= N) return;
    int n = base + six;
    int nc = min(n, N - 1);
    int r0 = l >> 3, m = l & 7;

    const float* xr = x + (size_t)nc * 64;
    float4 xa = *(const float4*)(xr + quad * 8);
    float4 xb = *(const float4*)(xr + quad * 8 + 4);
    float4 xc = *(const float4*)(xr + 32 + quad * 8);
    float4 xd = *(const float4*)(xr + 32 + quad * 8 + 4);
    union { bf16x8 v; unsigned int u[4]; } b0, b1;
    b0.u[0] = pack2(xa.x, xa.y); b0.u[1] = pack2(xa.z, xa.w);
    b0.u[2] = pack2(xb.x, xb.y); b0.u[3] = pack2(xb.z, xb.w);
    b1.u[0] = pack2(xc.x, xc.y); b1.u[1] = pack2(xc.z, xc.w);
    b1.u[2] = pack2(xd.x, xd.y); b1.u[3] = pack2(xd.z, xd.w);

    // stage x-tile (64 cols) and flush to x0, coalesced
    *(uint4*)&sbuf[w][six][quad * 8]      = make_uint4(b0.u[0], b0.u[1], b0.u[2], b0.u[3]);
    *(uint4*)&sbuf[w][six][32 + quad * 8] = make_uint4(b1.u[0], b1.u[1], b1.u[2], b1.u[3]);
    __builtin_amdgcn_wave_barrier();
    #pragma unroll
    for (int c = 0; c < 2; ++c) {
        int r = r0 + c * 8;
        int n2 = base + r;
        if (n2 < N)
            *(uint4*)(x0 + (size_t)n2 * 64 + m * 8) = *(const uint4*)&sbuf[w][r][m * 8];
    }
    __builtin_amdgcn_wave_barrier();

    #pragma unroll
    for (int g = 0; g < 4; ++g) {
        f32x4v c[4];
        #pragma unroll
        for (int tt = 0; tt < 4; ++tt) {
            int t = g * 4 + tt;
            const unsigned short* wr = Wb + (size_t)(t * 16 + six) * 64;
            bf16x8 a0 = *(const bf16x8*)(wr + quad * 8);
            bf16x8 a1 = *(const bf16x8*)(wr + 32 + quad * 8);
            f32x4v cc = {0.f, 0.f, 0.f, 0.f};
            cc = __builtin_amdgcn_mfma_f32_16x16x32_bf16(a0, b0.v, cc, 0, 0, 0);
            cc = __builtin_amdgcn_mfma_f32_16x16x32_bf16(a1, b1.v, cc, 0, 0, 0);
            c[tt] = cc;
        }
        const float* bias = (g < 2) ? Wq_b : Wk_b;
        int cb = (g & 1) * 64 + quad * 4;
        float ss = 0.f;
        #pragma unroll
        for (int tt = 0; tt < 4; ++tt) {
            float4 bv = *(const float4*)(bias + cb + tt * 16);
            c[tt][0] += bv.x; c[tt][1] += bv.y; c[tt][2] += bv.z; c[tt][3] += bv.w;
            ss += c[tt][0] * c[tt][0] + c[tt][1] * c[tt][1]
                + c[tt][2] * c[tt][2] + c[tt][3] * c[tt][3];
        }
        ss += __shfl_xor(ss, 16, 64);
        ss += __shfl_xor(ss, 32, 64);
        float sc = rsqrtf(ss);
        // stage this 64-col half into LDS, then flush coalesced
        #pragma unroll
        for (int tt = 0; tt < 4; ++tt) {
            unsigned int u0 = pack2(c[tt][0] * sc, c[tt][1] * sc);
            unsigned int u1 = pack2(c[tt][2] * sc, c[tt][3] * sc);
            *(uint2*)&sbuf[w][six][tt * 16 + quad * 4] = make_uint2(u0, u1);
        }
        __builtin_amdgcn_wave_barrier();
        unsigned short* arr = (g < 2) ? q : kq;
        #pragma unroll
        for (int c2 = 0; c2 < 2; ++c2) {
            int r = r0 + c2 * 8;
            int n2 = base + r;
            if (n2 < N)
                *(uint4*)(arr + (size_t)n2 * 128 + (g & 1) * 64 + m * 8)
                    = *(const uint4*)&sbuf[w][r][m * 8];
        }
        __builtin_amdgcn_wave_barrier();
    }
}

// ---- degree + slot assignment (slot = this edge's index within its row) ----
__global__ void k_deg(const int* __restrict__ row, int* __restrict__ deg,
                      int* __restrict__ slot, int E) {
    int e = blockIdx.x * 256 + threadIdx.x;
    if (e < E) slot[e] = atomicAdd(&deg[row[e]], 1);
}

// ---- exclusive scan of deg -> rowstart (+ dis folded in) -------------------
__global__ void k_scan1(const int* __restrict__ deg, int* __restrict__ rowstart,
                        int* __restrict__ bsum, float* __restrict__ dis, int N) {
    __shared__ int sh[256];
    int t = threadIdx.x, n = blockIdx.x * 256 + t;
    int v = (n < N) ? deg[n] : 0;
    if (n < N) dis[n] = v > 0 ? rsqrtf((float)v) : 0.f;
    sh[t] = v; __syncthreads();
    #pragma unroll
    for (int off = 1; off < 256; off <<= 1) {
        int add = (t >= off) ? sh[t - off] : 0;
        __syncthreads();
        sh[t] += add;
        __syncthreads();
    }
    if (n < N) rowstart[n] = sh[t] - v;
    if (t == 255) bsum[blockIdx.x] = sh[255];
}

__global__ void k_scan2(int* __restrict__ bsum, int nb) {
    __shared__ int sh[512];
    __shared__ int carry;
    int t = threadIdx.x;
    if (t == 0) carry = 0;
    __syncthreads();
    for (int base = 0; base < nb; base += 512) {
        int idx = base + t;
        int v = (idx < nb) ? bsum[idx] : 0;
        sh[t] = v; __syncthreads();
        for (int off = 1; off < 512; off <<= 1) {
            int add = (t >= off) ? sh[t - off] : 0;
            __syncthreads();
            sh[t] += add;
            __syncthreads();
        }
        if (idx < nb) bsum[idx] = sh[t] - v + carry;
        __syncthreads();
        if (t == 0) carry += sh[511];
        __syncthreads();
    }
}

__global__ void k_scan3(int* __restrict__ rowstart, const int* __restrict__ bsum, int N, int E) {
    int n = blockIdx.x * 256 + threadIdx.x;
    if (n < N) rowstart[n] += bsum[blockIdx.x];
    if (n == 0) rowstart[N] = E;
}

// ---- CSR fill: NO atomic (slot precomputed), ONE int4 16B store per edge ---
__global__ void k_fill(const int* __restrict__ eidx, const float* __restrict__ dis,
                       const int* __restrict__ rowstart, const int* __restrict__ slot,
                       int4* __restrict__ csr_pack, const int* __restrict__ eattr, int E) {
    int e = blockIdx.x * 256 + threadIdx.x;
    if (e >= E) return;
    int r = eidx[e], c = eidx[E + e];
    float wv = dis[r] * dis[c];
    int a0 = eattr[e * 3 + 0], a1 = eattr[e * 3 + 1], a2 = eattr[e * 3 + 2];
    int idx = rowstart[r] + slot[e];
    int4 v;
    v.x = c;
    v.y = __float_as_int(wv);
    v.z = a0 | (a1 << 8) | (a2 << 16);
    v.w = 0;
    csr_pack[idx] = v;
}

// ---- msg_edge[n,64] in BF16; bond table in LDS, wave per node --------------
__global__ __launch_bounds__(256) void k_msg(
    const int* __restrict__ rowstart, const int4* __restrict__ csr_pack,
    const float* __restrict__ bond, unsigned short* __restrict__ msgb, int N) {
    __shared__ float bl[1536];
    int t = threadIdx.x, w = t >> 6, l = t & 63;
    for (int i = t; i < 1536; i += 256) bl[i] = bond[i];
    __syncthreads();
    for (int n = blockIdx.x * 4 + w; n < N; n += gridDim.x * 4) {
        int s0 = rowstart[n], s1 = rowstart[n + 1];
        float m = 0.f;
        #pragma unroll 4
        for (int i = s0; i < s1; ++i) {
            int4 pk = csr_pack[i];
            float wv = __int_as_float(pk.y);
            int att = pk.z;
            m += wv * (bl[(att & 255) * 64 + l] + bl[(8 + ((att >> 8) & 255)) * 64 + l]
                     + bl[(16 + (att >> 16)) * 64 + l]);
        }
        msgb[(size_t)n * 64 + l] = f2b_u(m);
    }
}

// ---- ksum stage 1: per-chunk partial (plain stores) ------------------------
__global__ __launch_bounds__(256) void k_ksump(
    const unsigned short* __restrict__ kq, const int* __restrict__ ptr,
    const int* __restrict__ cptr, float* __restrict__ partKS, int B)
{
    int cid = blockIdx.x;
    if (cid >= cptr[B]) return;
    int lo = 0, hi = B - 1;
    while (lo < hi) { int mid = (lo + hi + 1) >> 1; if (cptr[mid] <= cid) lo = mid; else hi = mid - 1; }
    int b = lo;
    int start = ptr[b] + (cid - cptr[b]) * CHUNK;
    int end = min(start + CHUNK, ptr[b + 1]);
    int t = threadIdx.x, r = t >> 7, col = t & 127;
    float a = 0.f;
    for (int n = start + r; n < end; n += 2)
        a += b2f_u(kq[(size_t)n * 128 + col]);
    __shared__ float sh[256];
    sh[t] = a;
    __syncthreads();
    if (t < 128) partKS[(size_t)cid * 128 + t] = sh[t] + sh[t + 128];
}

// ---- ksum stage 2: sum chunk partials per graph ----------------------------
__global__ __launch_bounds__(128) void k_ksr(
    const float* __restrict__ partKS, const int* __restrict__ cptr,
    float* __restrict__ ksum, int B)
{
    int b = blockIdx.x, t = threadIdx.x;
    float s = 0.f;
    int c0 = cptr[b], c1 = cptr[b + 1];
    for (int c = c0; c < c1; ++c) s += partKS[(size_t)c * 128 + t];
    ksum[b * 128 + t] = s;
}

// ---- denom[n][h] = q[n,h,:].ksum[b,h,:] + n_nodes[b] -----------------------
__global__ __launch_bounds__(256) void k_denom(
    const unsigned short* __restrict__ q, const float* __restrict__ ksum,
    const int* __restrict__ batch, const int* __restrict__ nn,
    float* __restrict__ denom, int N)
{
    int w = threadIdx.x >> 6, l = threadIdx.x & 63;
    int n = blockIdx.x * 4 + w;
    if (n >= N) return;
    int b = batch[n];
    float d0 = b2f_u(q[(size_t)n * 128 + l]) * ksum[b * 128 + l];
    float d1 = b2f_u(q[(size_t)n * 128 + 64 + l]) * ksum[b * 128 + 64 + l];
    d0 = wave_reduce_sum(d0);
    d1 = wave_reduce_sum(d1);
    if (l == 0) {
        float nf = (float)nn[b];
        denom[n * 2 + 0] = d0 + nf;
        denom[n * 2 + 1] = d1 + nf;
    }
}

// ---- stage 1: per-chunk kv via MFMA; pitch/hoff select x0 vs curA ----------
__global__ __launch_bounds__(256) void k_kvp(
    const unsigned short* __restrict__ kq, const unsigned short* __restrict__ cur,
    int pitch, int hoff,
    const int* __restrict__ ptr, const int* __restrict__ cptr,
    unsigned short* __restrict__ partKV, float* __restrict__ partVS, int B)
{
    int cid = blockIdx.x;
    if (cid >= cptr[B]) return;
    int lo = 0, hi = B - 1;
    while (lo < hi) { int mid = (lo + hi + 1) >> 1; if (cptr[mid] <= cid) lo = mid; else hi = mid - 1; }
    int b = lo;
    int start = ptr[b] + (cid - cptr[b]) * CHUNK;
    int end = min(start + CHUNK, ptr[b + 1]);

    int w = threadIdx.x >> 6, l = threadIdx.x & 63;
    int h = w >> 1, dhalf = w & 1;
    int six = l & 15, quad = l >> 4;

    f32x4v c00 = {0,0,0,0}, c01 = {0,0,0,0}, c10 = {0,0,0,0}, c11 = {0,0,0,0};
    f32x4v c20 = {0,0,0,0}, c21 = {0,0,0,0}, c30 = {0,0,0,0}, c31 = {0,0,0,0};
    f32x4v s0 = {0,0,0,0}, s1 = {0,0,0,0}, s2 = {0,0,0,0}, s3 = {0,0,0,0};

    const unsigned short ONE = 0x3F80;  // bf16 1.0

    for (int nb = start; nb < end; nb += 32) {
        union { bf16x8 v; unsigned short s[8]; } a0u, a1u, a2u, a3u, b0u, b1u, onu;
        if (nb + 32 <= end) {
            const unsigned short* vb = cur + (size_t)(nb + quad * 8) * pitch + h * hoff + six;
            const unsigned short* kb = kq  + (size_t)(nb + quad * 8) * 128 + h * 64 + dhalf * 32 + six;
            #pragma unroll
            for (int j = 0; j < 8; ++j) {
                a0u.s[j] = vb[j * pitch];
                a1u.s[j] = vb[j * pitch + 16];
                a2u.s[j] = vb[j * pitch + 32];
                a3u.s[j] = vb[j * pitch + 48];
                b0u.s[j] = kb[j * 128];
                b1u.s[j] = kb[j * 128 + 16];
                onu.s[j] = ONE;
            }
        } else {
            #pragma unroll
            for (int j = 0; j < 8; ++j) {
                int nd = nb + quad * 8 + j;
                int ndc = min(nd, end - 1);
                bool ok = nd < end;
                const unsigned short* vb = cur + (size_t)ndc * pitch + h * hoff + six;
                const unsigned short* kb = kq  + (size_t)ndc * 128 + h * 64 + dhalf * 32 + six;
                a0u.s[j] = vb[0];
                a1u.s[j] = vb[16];
                a2u.s[j] = vb[32];
                a3u.s[j] = vb[48];
                b0u.s[j] = ok ? kb[0]  : (unsigned short)0;
                b1u.s[j] = ok ? kb[16] : (unsigned short)0;
                onu.s[j] = ok ? ONE : (unsigned short)0;
            }
        }
        c00 = __builtin_amdgcn_mfma_f32_16x16x32_bf16(a0u.v, b0u.v, c00, 0, 0, 0);
        c01 = __builtin_amdgcn_mfma_f32_16x16x32_bf16(a0u.v, b1u.v, c01, 0, 0, 0);
        c10 = __builtin_amdgcn_mfma_f32_16x16x32_bf16(a1u.v, b0u.v, c10, 0, 0, 0);
        c11 = __builtin_amdgcn_mfma_f32_16x16x32_bf16(a1u.v, b1u.v, c11, 0, 0, 0);
        c20 = __builtin_amdgcn_mfma_f32_16x16x32_bf16(a2u.v, b0u.v, c20, 0, 0, 0);
        c21 = __builtin_amdgcn_mfma_f32_16x16x32_bf16(a2u.v, b1u.v, c21, 0, 0, 0);
        c30 = __builtin_amdgcn_mfma_f32_16x16x32_bf16(a3u.v, b0u.v, c30, 0, 0, 0);
        c31 = __builtin_amdgcn_mfma_f32_16x16x32_bf16(a3u.v, b1u.v, c31, 0, 0, 0);
        s0  = __builtin_amdgcn_mfma_f32_16x16x32_bf16(a0u.v, onu.v, s0, 0, 0, 0);
        s1  = __builtin_amdgcn_mfma_f32_16x16x32_bf16(a1u.v, onu.v, s1, 0, 0, 0);
        s2  = __builtin_amdgcn_mfma_f32_16x16x32_bf16(a2u.v, onu.v, s2, 0, 0, 0);
        s3  = __builtin_amdgcn_mfma_f32_16x16x32_bf16(a3u.v, onu.v, s3, 0, 0, 0);
    }

    unsigned short* dst = partKV + (size_t)cid * 8192 + h * 4096 + dhalf * 32 + six;
    #pragma unroll
    for (int r = 0; r < 4; ++r) {
        int e = quad * 4 + r;
        dst[(e +  0) * 64 +  0] = f2b_u(c00[r]);
        dst[(e +  0) * 64 + 16] = f2b_u(c01[r]);
        dst[(e + 16) * 64 +  0] = f2b_u(c10[r]);
        dst[(e + 16) * 64 + 16] = f2b_u(c11[r]);
        dst[(e + 32) * 64 +  0] = f2b_u(c20[r]);
        dst[(e + 32) * 64 + 16] = f2b_u(c21[r]);
        dst[(e + 48) * 64 +  0] = f2b_u(c30[r]);
        dst[(e + 48) * 64 + 16] = f2b_u(c31[r]);
    }
    if (dhalf == 0 && six == 0) {
        float* vdst = partVS + (size_t)cid * 128 + h * 64;
        #pragma unroll
        for (int r = 0; r < 4; ++r) {
            int e = quad * 4 + r;
            vdst[e]      = s0[r];
            vdst[e + 16] = s1[r];
            vdst[e + 32] = s2[r];
            vdst[e + 48] = s3[r];
        }
    }
}

// ---- stage 2: sum bf16 partials -> kvT bf16 + vsum (256 blocks) ------------
__global__ __launch_bounds__(256) void k_red(
    const unsigned short* __restrict__ partKV, const float* __restrict__ partVS,
    const int* __restrict__ cptr, unsigned short* __restrict__ kvT_b,
    float* __restrict__ vsum, int B)
{
    int bid = blockIdx.x;
    int gh = bid >> 1, half = bid & 1;
    int g = gh >> 1, h = gh & 1;
    int c0 = cptr[g], c1 = cptr[g + 1];
    int t = threadIdx.x;
    int off = half * 2048 + t * 8;   // element offset within the 4096-elem strip
    float s[8];
    #pragma unroll
    for (int i = 0; i < 8; ++i) s[i] = 0.f;
    for (int c = c0; c < c1; ++c) {
        uint4 u = *(const uint4*)(partKV + (size_t)c * 8192 + h * 4096 + off);
        s[0] += asf(u.x << 16); s[1] += asf(u.x & 0xffff0000u);
        s[2] += asf(u.y << 16); s[3] += asf(u.y & 0xffff0000u);
        s[4] += asf(u.z << 16); s[5] += asf(u.z & 0xffff0000u);
        s[6] += asf(u.w << 16); s[7] += asf(u.w & 0xffff0000u);
    }
    unsigned int u[4];
    #pragma unroll
    for (int i = 0; i < 4; ++i) u[i] = pack2(s[2 * i], s[2 * i + 1]);
    *(uint4*)(kvT_b + (size_t)gh * 4096 + off) = make_uint4(u[0], u[1], u[2], u[3]);
    if (half == 0 && t < 64) {
        float vs = 0.f;
        for (int c = c0; c < c1; ++c) vs += partVS[(size_t)c * 128 + h * 64 + t];
        vsum[g * 128 + h * 64 + t] = vs;
    }
}

// ---- attn via MFMA on graph-aligned 16-node tiles; also adds 0.5*msg -------
__global__ __launch_bounds__(256) void k_attn(
    const unsigned short* __restrict__ q, const unsigned short* __restrict__ kvT,
    const float* __restrict__ vsum, const float* __restrict__ denom,
    const int* __restrict__ ptr, const int* __restrict__ tptr,
    const unsigned short* __restrict__ msgb,
    unsigned short* __restrict__ curB, int B)
{
    int w = threadIdx.x >> 6, l = threadIdx.x & 63;
    int tid = blockIdx.x * 4 + w;
    if (tid >= tptr[B]) return;
    int lo = 0, hi = B - 1;
    while (lo < hi) { int mid = (lo + hi + 1) >> 1; if (tptr[mid] <= tid) lo = mid; else hi = mid - 1; }
    int b0 = lo;
    int start = ptr[b0] + (tid - tptr[b0]) * 16;
    int end = min(start + 16, ptr[b0 + 1]);
    int quad = l >> 4, six = l & 15;
    int n = start + six;        // this lane's node (C column)
    int nc = min(n, end - 1);   // clamped for loads
    bool live = n < end;
    const unsigned short* mrow = msgb + (size_t)nc * 64;
    uint2 me[4];
    #pragma unroll
    for (int et = 0; et < 4; ++et) me[et] = *(const uint2*)(mrow + et * 16 + quad * 4);
    #pragma unroll
    for (int h = 0; h < 2; ++h) {
        const unsigned short* qrow = q + (size_t)nc * 128 + h * 64;
        bf16x8 qb0 = *(const bf16x8*)(qrow + quad * 8);        // B-frag k=quad*8+j
        bf16x8 qb1 = *(const bf16x8*)(qrow + 32 + quad * 8);
        const unsigned short* Bb = kvT + (size_t)(b0 * 2 + h) * 4096;
        float dn = denom[nc * 2 + h];
        const float* vsb = vsum + (b0 * 2 + h) * 64;
        #pragma unroll
        for (int et = 0; et < 4; ++et) {
            const unsigned short* arow = Bb + (size_t)(et * 16 + six) * 64;  // A m=e row
            bf16x8 a0 = *(const bf16x8*)(arow + quad * 8);
            bf16x8 a1 = *(const bf16x8*)(arow + 32 + quad * 8);
            f32x4v c = {0.f, 0.f, 0.f, 0.f};
            c = __builtin_amdgcn_mfma_f32_16x16x32_bf16(a0, qb0, c, 0, 0, 0);
            c = __builtin_amdgcn_mfma_f32_16x16x32_bf16(a1, qb1, c, 0, 0, 0);
            float4 vs = *(const float4*)(vsb + et * 16 + quad * 4);
            float m0 = asf(me[et].x << 16), m1 = asf(me[et].x & 0xffff0000u);
            float m2 = asf(me[et].y << 16), m3 = asf(me[et].y & 0xffff0000u);
            float v0 = 0.5f * (c[0] + vs.x) / dn + 0.5f * m0;
            float v1 = 0.5f * (c[1] + vs.y) / dn + 0.5f * m1;
            float v2 = 0.5f * (c[2] + vs.z) / dn + 0.5f * m2;
            float v3 = 0.5f * (c[3] + vs.w) / dn + 0.5f * m3;
            if (live) {
                uint2 st = make_uint2(pack2(v0, v1), pack2(v2, v3));
                *(uint2*)(curB + (size_t)n * 128 + h * 64 + et * 16 + quad * 4) = st;
            }
        }
    }
}

// ---- GCN gather + combine; src pitch 64 (x0, it=0) or 128 (curA) -----------
__global__ __launch_bounds__(256) void k_gcn(
    const unsigned short* __restrict__ src, int pitch,
    const int* __restrict__ rowstart, const int4* __restrict__ csr_pack,
    unsigned short* __restrict__ curB, unsigned short* __restrict__ acc,
    const unsigned short* __restrict__ x0, int N, int first)
{
    // bijective XCD swizzle (m204)
    int orig = blockIdx.x, nwg = gridDim.x;
    int q8 = nwg >> 3, r8 = nwg & 7;
    int xcd = orig & 7, jj = orig >> 3;
    int swz = (xcd < r8 ? xcd * (q8 + 1) : r8 * (q8 + 1) + (xcd - r8) * q8) + jj;

    int w = threadIdx.x >> 6, l = threadIdx.x & 63;
    int qq = l >> 4, ql = l & 15;
    int half = qq >> 1;          // 0 -> node A, 1 -> node B
    int par  = qq & 1;           // parity within the node's edge list
    int nA = swz * 8 + w * 2;
    if (nA >= N) return;
    bool hasB = (nA + 1) < N;
    int myN = nA + half;
    bool live = myN < N;
    int s0  = rowstart[nA];
    int sA1 = rowstart[nA + 1];
    int s1  = hasB ? rowstart[nA + 2] : sA1;
    int base = half ? sA1 : s0;
    int lim  = half ? s1  : sA1;

    int e0 = 8 * ql + par * 4;
    size_t o = (size_t)myN * 128 + e0;
    uint2 ub = make_uint2(0, 0), ua = make_uint2(0, 0);
    if (live) {
        ub = *(const uint2*)(curB + o);
        ua = first ? *(const uint2*)(x0 + (size_t)myN * 64 + (e0 & 63))
                   : *(const uint2*)(acc + o);
    }

    int colofs = (8 * ql) & (pitch - 1);
    float g[8];
    #pragma unroll
    for (int j = 0; j < 8; ++j) g[j] = 0.f;
    const int2* cw2 = (const int2*)csr_pack;   // record stride 16B; take {col,w}
    #pragma unroll 2
    for (int i = base + par; i < lim; i += 2) {
        int2 cw = cw2[2 * i];
        float wv = __int_as_float(cw.y);
        uint4 u = *(const uint4*)(src + (size_t)cw.x * pitch + colofs);
        g[0] += wv * asf(u.x << 16); g[1] += wv * asf(u.x & 0xffff0000u);
        g[2] += wv * asf(u.y << 16); g[3] += wv * asf(u.y & 0xffff0000u);
        g[4] += wv * asf(u.z << 16); g[5] += wv * asf(u.z & 0xffff0000u);
        g[6] += wv * asf(u.w << 16); g[7] += wv * asf(u.w & 0xffff0000u);
    }
    #pragma unroll
    for (int j = 0; j < 8; ++j) g[j] += __shfl_xor(g[j], 16, 64);
    float s0v = par ? g[4] : g[0];
    float s1v = par ? g[5] : g[1];
    float s2v = par ? g[6] : g[2];
    float s3v = par ? g[7] : g[3];
    if (live) {
        float v0 = 0.5f * s0v + asf(ub.x << 16);
        float v1 = 0.5f * s1v + asf(ub.x & 0xffff0000u);
        float v2 = 0.5f * s2v + asf(ub.y << 16);
        float v3 = 0.5f * s3v + asf(ub.y & 0xffff0000u);
        *(uint2*)(curB + o) = make_uint2(pack2(v0, v1), pack2(v2, v3));
        float a0 = asf(ua.x << 16) + v0, a1 = asf(ua.x & 0xffff0000u) + v1;
        float a2 = asf(ua.y << 16) + v2, a3 = asf(ua.y & 0xffff0000u) + v3;
        *(uint2*)(acc + o) = make_uint2(pack2(a0, a1), pack2(a2, a3));
    }
}

// ---- out = (acc @ Wo^T + b) / 2 via MFMA -----------------------------------
__global__ __launch_bounds__(256) void k_outm(
    const unsigned short* __restrict__ acc, const unsigned short* __restrict__ Wob,
    const float* __restrict__ Wo_b, float* __restrict__ out, int N)
{
    int w = threadIdx.x >> 6, l = threadIdx.x & 63;
    int six = l & 15, quad = l >> 4;
    int base = (blockIdx.x * 4 + w) * 16;
    if (base >= N) return;
    int n = base + six;
    int nc = min(n, N - 1);
    const unsigned short* ar = acc + (size_t)nc * 128;
    bf16x8 b0 = *(const bf16x8*)(ar + quad * 8);
    bf16x8 b1 = *(const bf16x8*)(ar + 32 + quad * 8);
    bf16x8 b2 = *(const bf16x8*)(ar + 64 + quad * 8);
    bf16x8 b3 = *(const bf16x8*)(ar + 96 + quad * 8);
    #pragma unroll
    for (int t = 0; t < 4; ++t) {
        const unsigned short* wr = Wob + (size_t)(t * 16 + six) * 128;
        bf16x8 a0 = *(const bf16x8*)(wr + quad * 8);
        bf16x8 a1 = *(const bf16x8*)(wr + 32 + quad * 8);
        bf16x8 a2 = *(const bf16x8*)(wr + 64 + quad * 8);
        bf16x8 a3 = *(const bf16x8*)(wr + 96 + quad * 8);
        f32x4v c = {0.f, 0.f, 0.f, 0.f};
        c = __builtin_amdgcn_mfma_f32_16x16x32_bf16(a0, b0, c, 0, 0, 0);
        c = __builtin_amdgcn_mfma_f32_16x16x32_bf16(a1, b1, c, 0, 0, 0);
        c = __builtin_amdgcn_mfma_f32_16x16x32_bf16(a2, b2, c, 0, 0, 0);
        c = __builtin_amdgcn_mfma_f32_16x16x32_bf16(a3, b3, c, 0, 0, 0);
        if (n < N) {
            float4 bias = *(const float4*)(Wo_b + t * 16 + quad * 4);
            float4 o4;
            o4.x = (c[0] + bias.x) * 0.5f;
            o4.y = (c[1] + bias.y) * 0.5f;
            o4.z = (c[2] + bias.z) * 0.5f;
            o4.w = (c[3] + bias.w) * 0.5f;
            *(float4*)(out + (size_t)n * 64 + t * 16 + quad * 4) = o4;
        }
    }
}

extern "C" void kernel_launch(void* const* d_in, const int* in_sizes, int n_in,
                              void* d_out, int out_size, void* d_ws, size_t ws_size,
                              hipStream_t stream) {
    const float* x    = (const float*)d_in[0];
    const float* Wq_w = (const float*)d_in[1];
    const float* Wq_b = (const float*)d_in[2];
    const float* Wk_w = (const float*)d_in[3];
    const float* Wk_b = (const float*)d_in[4];
    const float* Wo_w = (const float*)d_in[5];
    const float* Wo_b = (const float*)d_in[6];
    const float* bond = (const float*)d_in[7];
    const int*   eidx = (const int*)d_in[8];
    const int*   eattr= (const int*)d_in[9];
    const int*   nn   = (const int*)d_in[10];
    float* out = (float*)d_out;
    int N = in_sizes[0] / 64;
    int E = in_sizes[9] / 3;
    int B = in_sizes[10];

    char* p = (char*)d_ws;
    auto alloc = [&](size_t bytes) { char* r = p; p += (bytes + 255) & ~(size_t)255; return r; };
    unsigned short* q    = (unsigned short*)alloc((size_t)N * 128 * 2);
    unsigned short* kq   = (unsigned short*)alloc((size_t)N * 128 * 2);
    unsigned short* x0   = (unsigned short*)alloc((size_t)N * 64 * 2);
    unsigned short* curA = (unsigned short*)alloc((size_t)N * 128 * 2);
    unsigned short* curB = (unsigned short*)alloc((size_t)N * 128 * 2);
    unsigned short* acc  = (unsigned short*)alloc((size_t)N * 128 * 2);
    int maxchunks = (N + CHUNK - 1) / CHUNK + B;
    int maxtiles  = (N + 15) / 16 + B;
    unsigned short* partKV = (unsigned short*)alloc((size_t)maxchunks * 8192 * 2);
    float* partVS = (float*)alloc((size_t)maxchunks * 128 * 4);
    float* partKS = (float*)alloc((size_t)maxchunks * 128 * 4);
    unsigned short* kvT_b = (unsigned short*)alloc((size_t)B * 2 * 64 * 64 * 2);
    float* vsum  = (float*)alloc((size_t)B * 128 * 4);
    float* ksum  = (float*)alloc((size_t)B * 128 * 4);
    float* denom = (float*)alloc((size_t)N * 2 * 4);
    float* dis   = (float*)alloc((size_t)N * 4);
    int* deg     = (int*)alloc((size_t)N * 4);
    int* rowstart= (int*)alloc((size_t)(N + 1) * 4);
    int* slot    = (int*)alloc((size_t)E * 4);
    int4* csr_pack = (int4*)alloc((size_t)E * 16);
    int* batch   = (int*)alloc((size_t)N * 4);
    int* ptr     = (int*)alloc((size_t)(B + 1) * 4);
    int* cptr    = (int*)alloc((size_t)(B + 1) * 4);
    int* tptr    = (int*)alloc((size_t)(B + 1) * 4);
    unsigned short* Wb = (unsigned short*)alloc(24576 * 2);
    int nb = (N + 255) / 256;
    int* bsum    = (int*)alloc((size_t)nb * 4);
    unsigned short* msgb = (unsigned short*)out;  // [N,64] bf16 aliased onto d_out; k_outm rewrites it last

    hipMemsetAsync(deg, 0, (size_t)N * 4, stream);

    k_ptr  <<<1, 64, 0, stream>>>(nn, ptr, cptr, tptr, B);
    k_batch<<<B, 256, 0, stream>>>(ptr, batch);
    k_wcvt <<<96, 256, 0, stream>>>(Wq_w, Wk_w, Wo_w, Wb);
    k_qkm  <<<(N + 63) / 64, 256, 0, stream>>>(x, Wb, Wq_b, Wk_b, q, kq, x0, N);
    k_deg  <<<(E + 255) / 256, 256, 0, stream>>>(eidx, deg, slot, E);
    k_scan1<<<nb, 256, 0, stream>>>(deg, rowstart, bsum, dis, N);
    k_scan2<<<1, 512, 0, stream>>>(bsum, nb);
    k_scan3<<<nb, 256, 0, stream>>>(rowstart, bsum, N, E);
    k_fill <<<(E + 255) / 256, 256, 0, stream>>>(eidx, dis, rowstart, slot, csr_pack, eattr, E);
    k_msg  <<<2048, 256, 0, stream>>>(rowstart, csr_pack, bond, msgb, N);
    k_ksump<<<maxchunks, 256, 0, stream>>>(kq, ptr, cptr, partKS, B);
    k_ksr  <<<B, 128, 0, stream>>>(partKS, cptr, ksum, B);
    k_denom<<<(N + 3) / 4, 256, 0, stream>>>(q, ksum, batch, nn, denom, N);

    int gcnblk = (N + 7) / 8;
    for (int it = 0; it < 4; ++it) {
        const unsigned short* src = (it == 0) ? x0 : curA;
        int pitch = (it == 0) ? 64 : 128;
        int hoff  = (it == 0) ? 0 : 64;
        k_kvp <<<maxchunks, 256, 0, stream>>>(kq, src, pitch, hoff, ptr, cptr, partKV, partVS, B);
        k_red <<<B * 4, 256, 0, stream>>>(partKV, partVS, cptr, kvT_b, vsum, B);
        k_attn<<<(maxtiles + 3) / 4, 256, 0, stream>>>(q, kvT_b, vsum, denom, ptr, tptr, msgb, curB, B);
        k_gcn <<<gcnblk, 256, 0, stream>>>(src, pitch, rowstart, csr_pack, curB, acc, x0, N, it == 0 ? 1 : 0);
        unsigned short* tmp = curA; curA = curB; curB = tmp;
    }
    k_outm<<<(N + 63) / 64, 256, 0, stream>>>(acc, Wb + 16384, Wo_b, out, N);
}

// Round 14
// 657.502 us; speedup vs baseline: 1.2291x; 1.0082x over previous
//
#include <hip/hip_runtime.h>
#include <hip/hip_bf16.h>

// GloAttnConv R25: remove the acc RMW from the k_gcn loop. k_gcn's 165MB/
// dispatch at 3.85 TB/s included 49MB of acc read+write per iteration. Now
// each iteration's cur lives in its own buffer (cur0..cur3); k_outm computes
// acc = x_broadcast + sum(cur_it) on the fly (111MB read once vs 24.6, and
// ONE bf16 rounding instead of 4 -> numerically closer to the fp32 ref).
// k_gcn: reads src-gather + csr + curB, writes curB only. Rest = R24.

typedef __attribute__((ext_vector_type(8))) short bf16x8;
typedef __attribute__((ext_vector_type(4))) float f32x4v;

#define CHUNK 128

__device__ __forceinline__ float asf(unsigned int u) { union { unsigned int i; float f; } v; v.i = u; return v.f; }
__device__ __forceinline__ float b2f_u(unsigned short u) { return asf((unsigned int)u << 16); }
__device__ __forceinline__ unsigned short f2b_u(float f) {
    __hip_bfloat16 h = __float2bfloat16(f);
    union { __hip_bfloat16 h; unsigned short u; } v; v.h = h; return v.u;
}
__device__ __forceinline__ unsigned int pack2(float a, float b) {
    return (unsigned int)f2b_u(a) | ((unsigned int)f2b_u(b) << 16);
}
__device__ __forceinline__ unsigned int add5(unsigned int a, unsigned int b,
                                             unsigned int c, unsigned int d, unsigned int e) {
    float lo = asf(a << 16) + asf(b << 16) + asf(c << 16) + asf(d << 16) + asf(e << 16);
    float hi = asf(a & 0xffff0000u) + asf(b & 0xffff0000u) + asf(c & 0xffff0000u)
             + asf(d & 0xffff0000u) + asf(e & 0xffff0000u);
    return pack2(lo, hi);
}
__device__ __forceinline__ float wave_reduce_sum(float v) {
    #pragma unroll
    for (int off = 32; off > 0; off >>= 1) v += __shfl_xor(v, off, 64);
    return v;
}

// ---- graph bookkeeping: node ptr + chunk ptr + 16-tile ptr ------------------
__global__ void k_ptr(const int* __restrict__ nn, int* __restrict__ ptr,
                      int* __restrict__ cptr, int* __restrict__ tptr, int B) {
    if (threadIdx.x == 0 && blockIdx.x == 0) {
        int s = 0, c = 0, t = 0; ptr[0] = 0; cptr[0] = 0; tptr[0] = 0;
        for (int i = 0; i < B; ++i) {
            s += nn[i]; ptr[i + 1] = s;
            c += (nn[i] + CHUNK - 1) / CHUNK; cptr[i + 1] = c;
            t += (nn[i] + 15) / 16; tptr[i + 1] = t;
        }
    }
}

__global__ void k_batch(const int* __restrict__ ptr, int* __restrict__ batch) {
    int b = blockIdx.x;
    int s = ptr[b], e = ptr[b + 1];
    for (int i = s + threadIdx.x; i < e; i += blockDim.x) batch[i] = b;
}

// ---- W -> bf16 stacked: [0,8192)=Wq, [8192,16384)=Wk, [16384,24576)=Wo ------
__global__ void k_wcvt(const float* __restrict__ Wq_w, const float* __restrict__ Wk_w,
                       const float* __restrict__ Wo_w, unsigned short* __restrict__ Wb) {
    int i = blockIdx.x * 256 + threadIdx.x;
    if (i < 24576) {
        float v = (i < 8192) ? Wq_w[i] : ((i < 16384) ? Wk_w[i - 8192] : Wo_w[i - 16384]);
        Wb[i] = f2b_u(v);
    }
}

// ---- q/k projection via MFMA + L2-normalize; writes q, kq, x0[N][64] -------
__global__ __launch_bounds__(256) void k_qkm(
    const float* __restrict__ x, const unsigned short* __restrict__ Wb,
    const float* __restrict__ Wq_b, const float* __restrict__ Wk_b,
    unsigned short* __restrict__ q, unsigned short* __restrict__ kq,
    unsigned short* __restrict__ x0, int N)
{
    __shared__ unsigned short sbuf[4][16][72];   // per-wave 16x64 tile, stride 72
    int w = threadIdx.x >> 6, l = threadIdx.x & 63;
    int six = l & 15, quad = l >> 4;
    int base = (blockIdx.x * 4 + w) * 16;
    if (base >= N) return;
    int n = base + six;
    int nc = min(n, N - 1);
    int r0 = l >> 3, m = l & 7;

    const float* xr = x + (size_t)nc * 64;
    float4 xa = *(const float4*)(xr + quad * 8);
    float4 xb = *(const float4*)(xr + quad * 8 + 4);
    float4 xc = *(const float4*)(xr + 32 + quad * 8);
    float4 xd = *(const float4*)(xr + 32 + quad * 8 + 4);
    union { bf16x8 v; unsigned int u[4]; } b0, b1;
    b0.u[0] = pack2(xa.x, xa.y); b0.u[1] = pack2(xa.z, xa.w);
    b0.u[2] = pack2(xb.x, xb.y); b0.u[3] = pack2(xb.z, xb.w);
    b1.u[0] = pack2(xc.x, xc.y); b1.u[1] = pack2(xc.z, xc.w);
    b1.u[2] = pack2(xd.x, xd.y); b1.u[3] = pack2(xd.z, xd.w);

    // stage x-tile (64 cols) and flush to x0, coalesced
    *(uint4*)&sbuf[w][six][quad * 8]      = make_uint4(b0.u[0], b0.u[1], b0.u[2], b0.u[3]);
    *(uint4*)&sbuf[w][six][32 + quad * 8] = make_uint4(b1.u[0], b1.u[1], b1.u[2], b1.u[3]);
    __builtin_amdgcn_wave_barrier();
    #pragma unroll
    for (int c = 0; c < 2; ++c) {
        int r = r0 + c * 8;
        int n2 = base + r;
        if (n2 < N)
            *(uint4*)(x0 + (size_t)n2 * 64 + m * 8) = *(const uint4*)&sbuf[w][r][m * 8];
    }
    __builtin_amdgcn_wave_barrier();

    #pragma unroll
    for (int g = 0; g < 4; ++g) {
        f32x4v c[4];
        #pragma unroll
        for (int tt = 0; tt < 4; ++tt) {
            int t = g * 4 + tt;
            const unsigned short* wr = Wb + (size_t)(t * 16 + six) * 64;
            bf16x8 a0 = *(const bf16x8*)(wr + quad * 8);
            bf16x8 a1 = *(const bf16x8*)(wr + 32 + quad * 8);
            f32x4v cc = {0.f, 0.f, 0.f, 0.f};
            cc = __builtin_amdgcn_mfma_f32_16x16x32_bf16(a0, b0.v, cc, 0, 0, 0);
            cc = __builtin_amdgcn_mfma_f32_16x16x32_bf16(a1, b1.v, cc, 0, 0, 0);
            c[tt] = cc;
        }
        const float* bias = (g < 2) ? Wq_b : Wk_b;
        int cb = (g & 1) * 64 + quad * 4;
        float ss = 0.f;
        #pragma unroll
        for (int tt = 0; tt < 4; ++tt) {
            float4 bv = *(const float4*)(bias + cb + tt * 16);
            c[tt][0] += bv.x; c[tt][1] += bv.y; c[tt][2] += bv.z; c[tt][3] += bv.w;
            ss += c[tt][0] * c[tt][0] + c[tt][1] * c[tt][1]
                + c[tt][2] * c[tt][2] + c[tt][3] * c[tt][3];
        }
        ss += __shfl_xor(ss, 16, 64);
        ss += __shfl_xor(ss, 32, 64);
        float sc = rsqrtf(ss);
        // stage this 64-col half into LDS, then flush coalesced
        #pragma unroll
        for (int tt = 0; tt < 4; ++tt) {
            unsigned int u0 = pack2(c[tt][0] * sc, c[tt][1] * sc);
            unsigned int u1 = pack2(c[tt][2] * sc, c[tt][3] * sc);
            *(uint2*)&sbuf[w][six][tt * 16 + quad * 4] = make_uint2(u0, u1);
        }
        __builtin_amdgcn_wave_barrier();
        unsigned short* arr = (g < 2) ? q : kq;
        #pragma unroll
        for (int c2 = 0; c2 < 2; ++c2) {
            int r = r0 + c2 * 8;
            int n2 = base + r;
            if (n2 < N)
                *(uint4*)(arr + (size_t)n2 * 128 + (g & 1) * 64 + m * 8)
                    = *(const uint4*)&sbuf[w][r][m * 8];
        }
        __builtin_amdgcn_wave_barrier();
    }
}

// ---- degree + slot assignment (slot = this edge's index within its row) ----
__global__ void k_deg(const int* __restrict__ row, int* __restrict__ deg,
                      int* __restrict__ slot, int E) {
    int e = blockIdx.x * 256 + threadIdx.x;
    if (e < E) slot[e] = atomicAdd(&deg[row[e]], 1);
}

// ---- exclusive scan of deg -> rowstart (+ dis folded in) -------------------
__global__ void k_scan1(const int* __restrict__ deg, int* __restrict__ rowstart,
                        int* __restrict__ bsum, float* __restrict__ dis, int N) {
    __shared__ int sh[256];
    int t = threadIdx.x, n = blockIdx.x * 256 + t;
    int v = (n < N) ? deg[n] : 0;
    if (n < N) dis[n] = v > 0 ? rsqrtf((float)v) : 0.f;
    sh[t] = v; __syncthreads();
    #pragma unroll
    for (int off = 1; off < 256; off <<= 1) {
        int add = (t >= off) ? sh[t - off] : 0;
        __syncthreads();
        sh[t] += add;
        __syncthreads();
    }
    if (n < N) rowstart[n] = sh[t] - v;
    if (t == 255) bsum[blockIdx.x] = sh[255];
}

__global__ void k_scan2(int* __restrict__ bsum, int nb) {
    __shared__ int sh[512];
    __shared__ int carry;
    int t = threadIdx.x;
    if (t == 0) carry = 0;
    __syncthreads();
    for (int base = 0; base < nb; base += 512) {
        int idx = base + t;
        int v = (idx < nb) ? bsum[idx] : 0;
        sh[t] = v; __syncthreads();
        for (int off = 1; off < 512; off <<= 1) {
            int add = (t >= off) ? sh[t - off] : 0;
            __syncthreads();
            sh[t] += add;
            __syncthreads();
        }
        if (idx < nb) bsum[idx] = sh[t] - v + carry;
        __syncthreads();
        if (t == 0) carry += sh[511];
        __syncthreads();
    }
}

__global__ void k_scan3(int* __restrict__ rowstart, const int* __restrict__ bsum, int N, int E) {
    int n = blockIdx.x * 256 + threadIdx.x;
    if (n < N) rowstart[n] += bsum[blockIdx.x];
    if (n == 0) rowstart[N] = E;
}

// ---- CSR fill: NO atomic (slot precomputed), ONE int4 16B store per edge ---
__global__ void k_fill(const int* __restrict__ eidx, const float* __restrict__ dis,
                       const int* __restrict__ rowstart, const int* __restrict__ slot,
                       int4* __restrict__ csr_pack, const int* __restrict__ eattr, int E) {
    int e = blockIdx.x * 256 + threadIdx.x;
    if (e >= E) return;
    int r = eidx[e], c = eidx[E + e];
    float wv = dis[r] * dis[c];
    int a0 = eattr[e * 3 + 0], a1 = eattr[e * 3 + 1], a2 = eattr[e * 3 + 2];
    int idx = rowstart[r] + slot[e];
    int4 v;
    v.x = c;
    v.y = __float_as_int(wv);
    v.z = a0 | (a1 << 8) | (a2 << 16);
    v.w = 0;
    csr_pack[idx] = v;
}

// ---- msg_edge[n,64] in BF16; bond table in LDS, wave per node --------------
__global__ __launch_bounds__(256) void k_msg(
    const int* __restrict__ rowstart, const int4* __restrict__ csr_pack,
    const float* __restrict__ bond, unsigned short* __restrict__ msgb, int N) {
    __shared__ float bl[1536];
    int t = threadIdx.x, w = t >> 6, l = t & 63;
    for (int i = t; i < 1536; i += 256) bl[i] = bond[i];
    __syncthreads();
    for (int n = blockIdx.x * 4 + w; n < N; n += gridDim.x * 4) {
        int s0 = rowstart[n], s1 = rowstart[n + 1];
        float m = 0.f;
        #pragma unroll 4
        for (int i = s0; i < s1; ++i) {
            int4 pk = csr_pack[i];
            float wv = __int_as_float(pk.y);
            int att = pk.z;
            m += wv * (bl[(att & 255) * 64 + l] + bl[(8 + ((att >> 8) & 255)) * 64 + l]
                     + bl[(16 + (att >> 16)) * 64 + l]);
        }
        msgb[(size_t)n * 64 + l] = f2b_u(m);
    }
}

// ---- ksum stage 1: per-chunk partial (plain stores) ------------------------
__global__ __launch_bounds__(256) void k_ksump(
    const unsigned short* __restrict__ kq, const int* __restrict__ ptr,
    const int* __restrict__ cptr, float* __restrict__ partKS, int B)
{
    int cid = blockIdx.x;
    if (cid >= cptr[B]) return;
    int lo = 0, hi = B - 1;
    while (lo < hi) { int mid = (lo + hi + 1) >> 1; if (cptr[mid] <= cid) lo = mid; else hi = mid - 1; }
    int b = lo;
    int start = ptr[b] + (cid - cptr[b]) * CHUNK;
    int end = min(start + CHUNK, ptr[b + 1]);
    int t = threadIdx.x, r = t >> 7, col = t & 127;
    float a = 0.f;
    for (int n = start + r; n < end; n += 2)
        a += b2f_u(kq[(size_t)n * 128 + col]);
    __shared__ float sh[256];
    sh[t] = a;
    __syncthreads();
    if (t < 128) partKS[(size_t)cid * 128 + t] = sh[t] + sh[t + 128];
}

// ---- ksum stage 2: sum chunk partials per graph ----------------------------
__global__ __launch_bounds__(128) void k_ksr(
    const float* __restrict__ partKS, const int* __restrict__ cptr,
    float* __restrict__ ksum, int B)
{
    int b = blockIdx.x, t = threadIdx.x;
    float s = 0.f;
    int c0 = cptr[b], c1 = cptr[b + 1];
    for (int c = c0; c < c1; ++c) s += partKS[(size_t)c * 128 + t];
    ksum[b * 128 + t] = s;
}

// ---- denom[n][h] = q[n,h,:].ksum[b,h,:] + n_nodes[b] -----------------------
__global__ __launch_bounds__(256) void k_denom(
    const unsigned short* __restrict__ q, const float* __restrict__ ksum,
    const int* __restrict__ batch, const int* __restrict__ nn,
    float* __restrict__ denom, int N)
{
    int w = threadIdx.x >> 6, l = threadIdx.x & 63;
    int n = blockIdx.x * 4 + w;
    if (n >= N) return;
    int b = batch[n];
    float d0 = b2f_u(q[(size_t)n * 128 + l]) * ksum[b * 128 + l];
    float d1 = b2f_u(q[(size_t)n * 128 + 64 + l]) * ksum[b * 128 + 64 + l];
    d0 = wave_reduce_sum(d0);
    d1 = wave_reduce_sum(d1);
    if (l == 0) {
        float nf = (float)nn[b];
        denom[n * 2 + 0] = d0 + nf;
        denom[n * 2 + 1] = d1 + nf;
    }
}

// ---- stage 1: per-chunk kv via MFMA; pitch/hoff select x0 vs cur -----------
__global__ __launch_bounds__(256) void k_kvp(
    const unsigned short* __restrict__ kq, const unsigned short* __restrict__ cur,
    int pitch, int hoff,
    const int* __restrict__ ptr, const int* __restrict__ cptr,
    unsigned short* __restrict__ partKV, float* __restrict__ partVS, int B)
{
    int cid = blockIdx.x;
    if (cid >= cptr[B]) return;
    int lo = 0, hi = B - 1;
    while (lo < hi) { int mid = (lo + hi + 1) >> 1; if (cptr[mid] <= cid) lo = mid; else hi = mid - 1; }
    int b = lo;
    int start = ptr[b] + (cid - cptr[b]) * CHUNK;
    int end = min(start + CHUNK, ptr[b + 1]);

    int w = threadIdx.x >> 6, l = threadIdx.x & 63;
    int h = w >> 1, dhalf = w & 1;
    int six = l & 15, quad = l >> 4;

    f32x4v c00 = {0,0,0,0}, c01 = {0,0,0,0}, c10 = {0,0,0,0}, c11 = {0,0,0,0};
    f32x4v c20 = {0,0,0,0}, c21 = {0,0,0,0}, c30 = {0,0,0,0}, c31 = {0,0,0,0};
    f32x4v s0 = {0,0,0,0}, s1 = {0,0,0,0}, s2 = {0,0,0,0}, s3 = {0,0,0,0};

    const unsigned short ONE = 0x3F80;  // bf16 1.0

    for (int nb = start; nb < end; nb += 32) {
        union { bf16x8 v; unsigned short s[8]; } a0u, a1u, a2u, a3u, b0u, b1u, onu;
        if (nb + 32 <= end) {
            const unsigned short* vb = cur + (size_t)(nb + quad * 8) * pitch + h * hoff + six;
            const unsigned short* kb = kq  + (size_t)(nb + quad * 8) * 128 + h * 64 + dhalf * 32 + six;
            #pragma unroll
            for (int j = 0; j < 8; ++j) {
                a0u.s[j] = vb[j * pitch];
                a1u.s[j] = vb[j * pitch + 16];
                a2u.s[j] = vb[j * pitch + 32];
                a3u.s[j] = vb[j * pitch + 48];
                b0u.s[j] = kb[j * 128];
                b1u.s[j] = kb[j * 128 + 16];
                onu.s[j] = ONE;
            }
        } else {
            #pragma unroll
            for (int j = 0; j < 8; ++j) {
                int nd = nb + quad * 8 + j;
                int ndc = min(nd, end - 1);
                bool ok = nd < end;
                const unsigned short* vb = cur + (size_t)ndc * pitch + h * hoff + six;
                const unsigned short* kb = kq  + (size_t)ndc * 128 + h * 64 + dhalf * 32 + six;
                a0u.s[j] = vb[0];
                a1u.s[j] = vb[16];
                a2u.s[j] = vb[32];
                a3u.s[j] = vb[48];
                b0u.s[j] = ok ? kb[0]  : (unsigned short)0;
                b1u.s[j] = ok ? kb[16] : (unsigned short)0;
                onu.s[j] = ok ? ONE : (unsigned short)0;
            }
        }
        c00 = __builtin_amdgcn_mfma_f32_16x16x32_bf16(a0u.v, b0u.v, c00, 0, 0, 0);
        c01 = __builtin_amdgcn_mfma_f32_16x16x32_bf16(a0u.v, b1u.v, c01, 0, 0, 0);
        c10 = __builtin_amdgcn_mfma_f32_16x16x32_bf16(a1u.v, b0u.v, c10, 0, 0, 0);
        c11 = __builtin_amdgcn_mfma_f32_16x16x32_bf16(a1u.v, b1u.v, c11, 0, 0, 0);
        c20 = __builtin_amdgcn_mfma_f32_16x16x32_bf16(a2u.v, b0u.v, c20, 0, 0, 0);
        c21 = __builtin_amdgcn_mfma_f32_16x16x32_bf16(a2u.v, b1u.v, c21, 0, 0, 0);
        c30 = __builtin_amdgcn_mfma_f32_16x16x32_bf16(a3u.v, b0u.v, c30, 0, 0, 0);
        c31 = __builtin_amdgcn_mfma_f32_16x16x32_bf16(a3u.v, b1u.v, c31, 0, 0, 0);
        s0  = __builtin_amdgcn_mfma_f32_16x16x32_bf16(a0u.v, onu.v, s0, 0, 0, 0);
        s1  = __builtin_amdgcn_mfma_f32_16x16x32_bf16(a1u.v, onu.v, s1, 0, 0, 0);
        s2  = __builtin_amdgcn_mfma_f32_16x16x32_bf16(a2u.v, onu.v, s2, 0, 0, 0);
        s3  = __builtin_amdgcn_mfma_f32_16x16x32_bf16(a3u.v, onu.v, s3, 0, 0, 0);
    }

    unsigned short* dst = partKV + (size_t)cid * 8192 + h * 4096 + dhalf * 32 + six;
    #pragma unroll
    for (int r = 0; r < 4; ++r) {
        int e = quad * 4 + r;
        dst[(e +  0) * 64 +  0] = f2b_u(c00[r]);
        dst[(e +  0) * 64 + 16] = f2b_u(c01[r]);
        dst[(e + 16) * 64 +  0] = f2b_u(c10[r]);
        dst[(e + 16) * 64 + 16] = f2b_u(c11[r]);
        dst[(e + 32) * 64 +  0] = f2b_u(c20[r]);
        dst[(e + 32) * 64 + 16] = f2b_u(c21[r]);
        dst[(e + 48) * 64 +  0] = f2b_u(c30[r]);
        dst[(e + 48) * 64 + 16] = f2b_u(c31[r]);
    }
    if (dhalf == 0 && six == 0) {
        float* vdst = partVS + (size_t)cid * 128 + h * 64;
        #pragma unroll
        for (int r = 0; r < 4; ++r) {
            int e = quad * 4 + r;
            vdst[e]      = s0[r];
            vdst[e + 16] = s1[r];
            vdst[e + 32] = s2[r];
            vdst[e + 48] = s3[r];
        }
    }
}

// ---- stage 2: sum bf16 partials -> kvT bf16 + vsum (256 blocks) ------------
__global__ __launch_bounds__(256) void k_red(
    const unsigned short* __restrict__ partKV, const float* __restrict__ partVS,
    const int* __restrict__ cptr, unsigned short* __restrict__ kvT_b,
    float* __restrict__ vsum, int B)
{
    int bid = blockIdx.x;
    int gh = bid >> 1, half = bid & 1;
    int g = gh >> 1, h = gh & 1;
    int c0 = cptr[g], c1 = cptr[g + 1];
    int t = threadIdx.x;
    int off = half * 2048 + t * 8;   // element offset within the 4096-elem strip
    float s[8];
    #pragma unroll
    for (int i = 0; i < 8; ++i) s[i] = 0.f;
    for (int c = c0; c < c1; ++c) {
        uint4 u = *(const uint4*)(partKV + (size_t)c * 8192 + h * 4096 + off);
        s[0] += asf(u.x << 16); s[1] += asf(u.x & 0xffff0000u);
        s[2] += asf(u.y << 16); s[3] += asf(u.y & 0xffff0000u);
        s[4] += asf(u.z << 16); s[5] += asf(u.z & 0xffff0000u);
        s[6] += asf(u.w << 16); s[7] += asf(u.w & 0xffff0000u);
    }
    unsigned int u[4];
    #pragma unroll
    for (int i = 0; i < 4; ++i) u[i] = pack2(s[2 * i], s[2 * i + 1]);
    *(uint4*)(kvT_b + (size_t)gh * 4096 + off) = make_uint4(u[0], u[1], u[2], u[3]);
    if (half == 0 && t < 64) {
        float vs = 0.f;
        for (int c = c0; c < c1; ++c) vs += partVS[(size_t)c * 128 + h * 64 + t];
        vsum[g * 128 + h * 64 + t] = vs;
    }
}

// ---- attn via MFMA on graph-aligned 16-node tiles; also adds 0.5*msg -------
__global__ __launch_bounds__(256) void k_attn(
    const unsigned short* __restrict__ q, const unsigned short* __restrict__ kvT,
    const float* __restrict__ vsum, const float* __restrict__ denom,
    const int* __restrict__ ptr, const int* __restrict__ tptr,
    const unsigned short* __restrict__ msgb,
    unsigned short* __restrict__ curB, int B)
{
    int w = threadIdx.x >> 6, l = threadIdx.x & 63;
    int tid = blockIdx.x * 4 + w;
    if (tid >= tptr[B]) return;
    int lo = 0, hi = B - 1;
    while (lo < hi) { int mid = (lo + hi + 1) >> 1; if (tptr[mid] <= tid) lo = mid; else hi = mid - 1; }
    int b0 = lo;
    int start = ptr[b0] + (tid - tptr[b0]) * 16;
    int end = min(start + 16, ptr[b0 + 1]);
    int quad = l >> 4, six = l & 15;
    int n = start + six;        // this lane's node (C column)
    int nc = min(n, end - 1);   // clamped for loads
    bool live = n < end;
    const unsigned short* mrow = msgb + (size_t)nc * 64;
    uint2 me[4];
    #pragma unroll
    for (int et = 0; et < 4; ++et) me[et] = *(const uint2*)(mrow + et * 16 + quad * 4);
    #pragma unroll
    for (int h = 0; h < 2; ++h) {
        const unsigned short* qrow = q + (size_t)nc * 128 + h * 64;
        bf16x8 qb0 = *(const bf16x8*)(qrow + quad * 8);        // B-frag k=quad*8+j
        bf16x8 qb1 = *(const bf16x8*)(qrow + 32 + quad * 8);
        const unsigned short* Bb = kvT + (size_t)(b0 * 2 + h) * 4096;
        float dn = denom[nc * 2 + h];
        const float* vsb = vsum + (b0 * 2 + h) * 64;
        #pragma unroll
        for (int et = 0; et < 4; ++et) {
            const unsigned short* arow = Bb + (size_t)(et * 16 + six) * 64;  // A m=e row
            bf16x8 a0 = *(const bf16x8*)(arow + quad * 8);
            bf16x8 a1 = *(const bf16x8*)(arow + 32 + quad * 8);
            f32x4v c = {0.f, 0.f, 0.f, 0.f};
            c = __builtin_amdgcn_mfma_f32_16x16x32_bf16(a0, qb0, c, 0, 0, 0);
            c = __builtin_amdgcn_mfma_f32_16x16x32_bf16(a1, qb1, c, 0, 0, 0);
            float4 vs = *(const float4*)(vsb + et * 16 + quad * 4);
            float m0 = asf(me[et].x << 16), m1 = asf(me[et].x & 0xffff0000u);
            float m2 = asf(me[et].y << 16), m3 = asf(me[et].y & 0xffff0000u);
            float v0 = 0.5f * (c[0] + vs.x) / dn + 0.5f * m0;
            float v1 = 0.5f * (c[1] + vs.y) / dn + 0.5f * m1;
            float v2 = 0.5f * (c[2] + vs.z) / dn + 0.5f * m2;
            float v3 = 0.5f * (c[3] + vs.w) / dn + 0.5f * m3;
            if (live) {
                uint2 st = make_uint2(pack2(v0, v1), pack2(v2, v3));
                *(uint2*)(curB + (size_t)n * 128 + h * 64 + et * 16 + quad * 4) = st;
            }
        }
    }
}

// ---- GCN gather + combine; NO acc RMW (cur buffers summed in k_outm) -------
__global__ __launch_bounds__(256) void k_gcn(
    const unsigned short* __restrict__ src, int pitch,
    const int* __restrict__ rowstart, const int4* __restrict__ csr_pack,
    unsigned short* __restrict__ curB, int N)
{
    // bijective XCD swizzle (m204)
    int orig = blockIdx.x, nwg = gridDim.x;
    int q8 = nwg >> 3, r8 = nwg & 7;
    int xcd = orig & 7, jj = orig >> 3;
    int swz = (xcd < r8 ? xcd * (q8 + 1) : r8 * (q8 + 1) + (xcd - r8) * q8) + jj;

    int w = threadIdx.x >> 6, l = threadIdx.x & 63;
    int qq = l >> 4, ql = l & 15;
    int half = qq >> 1;          // 0 -> node A, 1 -> node B
    int par  = qq & 1;           // parity within the node's edge list
    int nA = swz * 8 + w * 2;
    if (nA >= N) return;
    bool hasB = (nA + 1) < N;
    int myN = nA + half;
    bool live = myN < N;
    int s0  = rowstart[nA];
    int sA1 = rowstart[nA + 1];
    int s1  = hasB ? rowstart[nA + 2] : sA1;
    int base = half ? sA1 : s0;
    int lim  = half ? s1  : sA1;

    int e0 = 8 * ql + par * 4;
    size_t o = (size_t)myN * 128 + e0;
    uint2 ub = make_uint2(0, 0);
    if (live) ub = *(const uint2*)(curB + o);

    int colofs = (8 * ql) & (pitch - 1);
    float g[8];
    #pragma unroll
    for (int j = 0; j < 8; ++j) g[j] = 0.f;
    const int2* cw2 = (const int2*)csr_pack;   // record stride 16B; take {col,w}
    #pragma unroll 2
    for (int i = base + par; i < lim; i += 2) {
        int2 cw = cw2[2 * i];
        float wv = __int_as_float(cw.y);
        uint4 u = *(const uint4*)(src + (size_t)cw.x * pitch + colofs);
        g[0] += wv * asf(u.x << 16); g[1] += wv * asf(u.x & 0xffff0000u);
        g[2] += wv * asf(u.y << 16); g[3] += wv * asf(u.y & 0xffff0000u);
        g[4] += wv * asf(u.z << 16); g[5] += wv * asf(u.z & 0xffff0000u);
        g[6] += wv * asf(u.w << 16); g[7] += wv * asf(u.w & 0xffff0000u);
    }
    #pragma unroll
    for (int j = 0; j < 8; ++j) g[j] += __shfl_xor(g[j], 16, 64);
    float s0v = par ? g[4] : g[0];
    float s1v = par ? g[5] : g[1];
    float s2v = par ? g[6] : g[2];
    float s3v = par ? g[7] : g[3];
    if (live) {
        float v0 = 0.5f * s0v + asf(ub.x << 16);
        float v1 = 0.5f * s1v + asf(ub.x & 0xffff0000u);
        float v2 = 0.5f * s2v + asf(ub.y << 16);
        float v3 = 0.5f * s3v + asf(ub.y & 0xffff0000u);
        *(uint2*)(curB + o) = make_uint2(pack2(v0, v1), pack2(v2, v3));
    }
}

// ---- out = ((x_bcast + sum cur_it) @ Wo^T + b) / 2 via MFMA ----------------
__global__ __launch_bounds__(256) void k_outm(
    const unsigned short* __restrict__ c0, const unsigned short* __restrict__ c1,
    const unsigned short* __restrict__ c2, const unsigned short* __restrict__ c3,
    const unsigned short* __restrict__ x0, const unsigned short* __restrict__ Wob,
    const float* __restrict__ Wo_b, float* __restrict__ out, int N)
{
    int w = threadIdx.x >> 6, l = threadIdx.x & 63;
    int six = l & 15, quad = l >> 4;
    int base = (blockIdx.x * 4 + w) * 16;
    if (base >= N) return;
    int n = base + six;
    int nc = min(n, N - 1);
    const unsigned short* xr = x0 + (size_t)nc * 64;
    uint4 xlo = *(const uint4*)(xr + quad * 8);
    uint4 xhi = *(const uint4*)(xr + 32 + quad * 8);
    union { bf16x8 v; unsigned int u[4]; } bfrag[4];
    #pragma unroll
    for (int f = 0; f < 4; ++f) {
        size_t off = (size_t)nc * 128 + f * 32 + quad * 8;
        uint4 u0 = *(const uint4*)(c0 + off);
        uint4 u1 = *(const uint4*)(c1 + off);
        uint4 u2 = *(const uint4*)(c2 + off);
        uint4 u3 = *(const uint4*)(c3 + off);
        uint4 xa = (f & 1) ? xhi : xlo;
        bfrag[f].u[0] = add5(xa.x, u0.x, u1.x, u2.x, u3.x);
        bfrag[f].u[1] = add5(xa.y, u0.y, u1.y, u2.y, u3.y);
        bfrag[f].u[2] = add5(xa.z, u0.z, u1.z, u2.z, u3.z);
        bfrag[f].u[3] = add5(xa.w, u0.w, u1.w, u2.w, u3.w);
    }
    #pragma unroll
    for (int t = 0; t < 4; ++t) {
        const unsigned short* wr = Wob + (size_t)(t * 16 + six) * 128;
        bf16x8 a0 = *(const bf16x8*)(wr + quad * 8);
        bf16x8 a1 = *(const bf16x8*)(wr + 32 + quad * 8);
        bf16x8 a2 = *(const bf16x8*)(wr + 64 + quad * 8);
        bf16x8 a3 = *(const bf16x8*)(wr + 96 + quad * 8);
        f32x4v c = {0.f, 0.f, 0.f, 0.f};
        c = __builtin_amdgcn_mfma_f32_16x16x32_bf16(a0, bfrag[0].v, c, 0, 0, 0);
        c = __builtin_amdgcn_mfma_f32_16x16x32_bf16(a1, bfrag[1].v, c, 0, 0, 0);
        c = __builtin_amdgcn_mfma_f32_16x16x32_bf16(a2, bfrag[2].v, c, 0, 0, 0);
        c = __builtin_amdgcn_mfma_f32_16x16x32_bf16(a3, bfrag[3].v, c, 0, 0, 0);
        if (n < N) {
            float4 bias = *(const float4*)(Wo_b + t * 16 + quad * 4);
            float4 o4;
            o4.x = (c[0] + bias.x) * 0.5f;
            o4.y = (c[1] + bias.y) * 0.5f;
            o4.z = (c[2] + bias.z) * 0.5f;
            o4.w = (c[3] + bias.w) * 0.5f;
            *(float4*)(out + (size_t)n * 64 + t * 16 + quad * 4) = o4;
        }
    }
}

extern "C" void kernel_launch(void* const* d_in, const int* in_sizes, int n_in,
                              void* d_out, int out_size, void* d_ws, size_t ws_size,
                              hipStream_t stream) {
    const float* x    = (const float*)d_in[0];
    const float* Wq_w = (const float*)d_in[1];
    const float* Wq_b = (const float*)d_in[2];
    const float* Wk_w = (const float*)d_in[3];
    const float* Wk_b = (const float*)d_in[4];
    const float* Wo_w = (const float*)d_in[5];
    const float* Wo_b = (const float*)d_in[6];
    const float* bond = (const float*)d_in[7];
    const int*   eidx = (const int*)d_in[8];
    const int*   eattr= (const int*)d_in[9];
    const int*   nn   = (const int*)d_in[10];
    float* out = (float*)d_out;
    int N = in_sizes[0] / 64;
    int E = in_sizes[9] / 3;
    int B = in_sizes[10];

    char* p = (char*)d_ws;
    auto alloc = [&](size_t bytes) { char* r = p; p += (bytes + 255) & ~(size_t)255; return r; };
    unsigned short* q    = (unsigned short*)alloc((size_t)N * 128 * 2);
    unsigned short* kq   = (unsigned short*)alloc((size_t)N * 128 * 2);
    unsigned short* x0   = (unsigned short*)alloc((size_t)N * 64 * 2);
    unsigned short* cur[4];
    for (int i = 0; i < 4; ++i) cur[i] = (unsigned short*)alloc((size_t)N * 128 * 2);
    int maxchunks = (N + CHUNK - 1) / CHUNK + B;
    int maxtiles  = (N + 15) / 16 + B;
    unsigned short* partKV = (unsigned short*)alloc((size_t)maxchunks * 8192 * 2);
    float* partVS = (float*)alloc((size_t)maxchunks * 128 * 4);
    float* partKS = (float*)alloc((size_t)maxchunks * 128 * 4);
    unsigned short* kvT_b = (unsigned short*)alloc((size_t)B * 2 * 64 * 64 * 2);
    float* vsum  = (float*)alloc((size_t)B * 128 * 4);
    float* ksum  = (float*)alloc((size_t)B * 128 * 4);
    float* denom = (float*)alloc((size_t)N * 2 * 4);
    float* dis   = (float*)alloc((size_t)N * 4);
    int* deg     = (int*)alloc((size_t)N * 4);
    int* rowstart= (int*)alloc((size_t)(N + 1) * 4);
    int* slot    = (int*)alloc((size_t)E * 4);
    int4* csr_pack = (int4*)alloc((size_t)E * 16);
    int* batch   = (int*)alloc((size_t)N * 4);
    int* ptr     = (int*)alloc((size_t)(B + 1) * 4);
    int* cptr    = (int*)alloc((size_t)(B + 1) * 4);
    int* tptr    = (int*)alloc((size_t)(B + 1) * 4);
    unsigned short* Wb = (unsigned short*)alloc(24576 * 2);
    int nb = (N + 255) / 256;
    int* bsum    = (int*)alloc((size_t)nb * 4);
    unsigned short* msgb = (unsigned short*)out;  // [N,64] bf16 aliased onto d_out; k_outm rewrites it last

    hipMemsetAsync(deg, 0, (size_t)N * 4, stream);

    k_ptr  <<<1, 64, 0, stream>>>(nn, ptr, cptr, tptr, B);
    k_batch<<<B, 256, 0, stream>>>(ptr, batch);
    k_wcvt <<<96, 256, 0, stream>>>(Wq_w, Wk_w, Wo_w, Wb);
    k_qkm  <<<(N + 63) / 64, 256, 0, stream>>>(x, Wb, Wq_b, Wk_b, q, kq, x0, N);
    k_deg  <<<(E + 255) / 256, 256, 0, stream>>>(eidx, deg, slot, E);
    k_scan1<<<nb, 256, 0, stream>>>(deg, rowstart, bsum, dis, N);
    k_scan2<<<1, 512, 0, stream>>>(bsum, nb);
    k_scan3<<<nb, 256, 0, stream>>>(rowstart, bsum, N, E);
    k_fill <<<(E + 255) / 256, 256, 0, stream>>>(eidx, dis, rowstart, slot, csr_pack, eattr, E);
    k_msg  <<<2048, 256, 0, stream>>>(rowstart, csr_pack, bond, msgb, N);
    k_ksump<<<maxchunks, 256, 0, stream>>>(kq, ptr, cptr, partKS, B);
    k_ksr  <<<B, 128, 0, stream>>>(partKS, cptr, ksum, B);
    k_denom<<<(N + 3) / 4, 256, 0, stream>>>(q, ksum, batch, nn, denom, N);

    int gcnblk = (N + 7) / 8;
    for (int it = 0; it < 4; ++it) {
        const unsigned short* src = (it == 0) ? x0 : cur[it - 1];
        int pitch = (it == 0) ? 64 : 128;
        int hoff  = (it == 0) ? 0 : 64;
        k_kvp <<<maxchunks, 256, 0, stream>>>(kq, src, pitch, hoff, ptr, cptr, partKV, partVS, B);
        k_red <<<B * 4, 256, 0, stream>>>(partKV, partVS, cptr, kvT_b, vsum, B);
        k_attn<<<(maxtiles + 3) / 4, 256, 0, stream>>>(q, kvT_b, vsum, denom, ptr, tptr, msgb, cur[it], B);
        k_gcn <<<gcnblk, 256, 0, stream>>>(src, pitch, rowstart, csr_pack, cur[it], N);
    }
    k_outm<<<(N + 63) / 64, 256, 0, stream>>>(cur[0], cur[1], cur[2], cur[3], x0, Wb + 16384, Wo_b, out, N);
}